// Round 8
// baseline (391.482 us; speedup 1.0000x reference)
//
#include <hip/hip_runtime.h>
#include <hip/hip_bf16.h>
#include <math.h>

#define N_NODES 100000
#define R 32
#define E_EDGES 3200000
#define F_IN 128
#define HDIM 16
#define CDIM 8
#define NOUT 512               // R * HDIM
#define M_PAD 100032           // 1563 * 64
#define NBUCK 391              // ceil(N_NODES / 256)
#define CAP 9216               // bucket capacity: mean 8184, +11.4 sigma
#define KEYS 8192              // 256 nodes * 32 rels per bucket
#define P1CHUNK 8192
#define PREP_BLKS 128          // NOUT*F_IN / 512
#define FRONT_GRID (NBUCK + PREP_BLKS)
#define GEMM_BLKS 1563         // M_PAD/64  (A-stationary: col loop inside)
#define MID_GRID (NBUCK + GEMM_BLKS)

typedef __attribute__((ext_vector_type(8))) short bf16x8;
typedef __attribute__((ext_vector_type(4))) float f32x4;
typedef __attribute__((ext_vector_type(2))) _Float16 f16x2;

static __device__ __forceinline__ unsigned short f2bf(float f) {
    unsigned int u = __float_as_uint(f);
    unsigned int r = (u + 0x7FFFu + ((u >> 16) & 1u)) >> 16;
    return (unsigned short)r;
}
static __device__ __forceinline__ float bfl(unsigned x) {
    return __uint_as_float(x << 16);
}
static __device__ __forceinline__ float bfh(unsigned x) {
    return __uint_as_float(x & 0xFFFF0000u);
}
static __device__ __forceinline__ f16x2 asf16x2(float f) {
    union { float f; f16x2 h; } u; u.f = f; return u.h;
}
static __device__ __forceinline__ float asflt(f16x2 h) {
    union { f16x2 h; float f; } u; u.h = h; return u.f;
}

#if __has_builtin(__builtin_amdgcn_fdot2)
static __device__ __forceinline__ float FDOT2(f16x2 a, f16x2 b, float c) {
    return __builtin_amdgcn_fdot2(a, b, c, false);
}
#else
static __device__ __forceinline__ float FDOT2(f16x2 a, f16x2 b, float c) {
    return c + (float)a.x * (float)b.x + (float)a.y * (float)b.y;
}
#endif

// ============ k_front: bucket-scatter ∥ W1 repack ============
// packed ebuf entry: dl(8b)<<22 | et(5b)<<17 | src(17b)
__global__ __launch_bounds__(512) void k_front(const int* __restrict__ src,
                                               const int* __restrict__ dst,
                                               const int* __restrict__ et,
                                               const float* __restrict__ W1,
                                               int* __restrict__ gcursor,
                                               unsigned int* __restrict__ ebuf,
                                               unsigned short* __restrict__ BmT) {
    __shared__ int sh[3 * NBUCK];
    int b = blockIdx.x, t = threadIdx.x;
    if (b < NBUCK) {
        int* hist = sh;
        int* rank = sh + NBUCK;
        int* base = sh + 2 * NBUCK;
        for (int j = t; j < NBUCK; j += 512) { hist[j] = 0; rank[j] = 0; }
        __syncthreads();
        int e0 = b * P1CHUNK;
        int e1 = e0 + P1CHUNK; if (e1 > E_EDGES) e1 = E_EDGES;
        int n4 = (e1 - e0) >> 2;
        const int4* d4 = (const int4*)(dst + e0);
        const int4* s4 = (const int4*)(src + e0);
        const int4* t4 = (const int4*)(et + e0);
        for (int i = t; i < n4; i += 512) {
            int4 v = d4[i];
            atomicAdd(&hist[v.x >> 8], 1);
            atomicAdd(&hist[v.y >> 8], 1);
            atomicAdd(&hist[v.z >> 8], 1);
            atomicAdd(&hist[v.w >> 8], 1);
        }
        __syncthreads();
        for (int j = t; j < NBUCK; j += 512)
            base[j] = hist[j] ? atomicAdd(&gcursor[j], hist[j]) : 0;
        __syncthreads();
        for (int i = t; i < n4; i += 512) {
            int4 dv = d4[i];
            int4 sv = s4[i];
            int4 tv = t4[i];
            int ds[4] = {dv.x, dv.y, dv.z, dv.w};
            int ss[4] = {sv.x, sv.y, sv.z, sv.w};
            int ts[4] = {tv.x, tv.y, tv.z, tv.w};
            #pragma unroll
            for (int u = 0; u < 4; ++u) {
                int d = ds[u];
                int bk = d >> 8;
                unsigned pk = ((unsigned)(d & 255) << 22) | ((unsigned)ts[u] << 17)
                            | (unsigned)ss[u];
                int lr = atomicAdd(&rank[bk], 1);
                ebuf[(size_t)bk * CAP + base[bk] + lr] = pk;
            }
        }
    } else {
        // W1 [R,128,16] -> BmT bf16 [512][128] (n=r*16+o, k=f)
        int i = (b - NBUCK) * 512 + t;
        int n = i >> 7;
        int f = i & 127;
        int r = n >> 4;
        int o = n & 15;
        BmT[i] = f2bf(W1[r * (F_IN * HDIM) + f * HDIM + o]);
    }
}

// ============ k_mid: per-bucket counting sort ∥ A-stationary MFMA GEMM ============
// final elist entry: len(10b)<<22 | et(5b)<<17 | src(17b); fixed bucket base b*CAP
__global__ __launch_bounds__(256) void k_mid(const unsigned int* __restrict__ ebuf,
                                             const int* __restrict__ gcursor,
                                             int2* __restrict__ rse,
                                             unsigned int* __restrict__ elist,
                                             const float* __restrict__ A,
                                             const unsigned short* __restrict__ BmT,
                                             unsigned short* __restrict__ C) {
    __shared__ __align__(16) char smem[52224 + 64];
    int b = blockIdx.x, t = threadIdx.x;
    if (b < NBUCK) {
        // ---- counting sort, 256 threads ----
        unsigned int* cnt = (unsigned int*)smem;       // 8192 * 4 = 32 KB
        int* wsum = (int*)(smem + 32768);              // 4 ints
        int cntE = gcursor[b];
        size_t e0 = (size_t)b * CAP;
        #pragma unroll
        for (int j = 0; j < KEYS / 256; ++j) cnt[t + j * 256] = 0;
        __syncthreads();
        for (int i = t; i < cntE; i += 256)
            atomicAdd(&cnt[ebuf[e0 + i] >> 17], 1u);   // key = dl*32 + et
        __syncthreads();
        int kbase = t * (KEYS / 256);
        int s = 0;
        #pragma unroll
        for (int j = 0; j < KEYS / 256; ++j) s += (int)cnt[kbase + j];
        int lane = t & 63, wv = t >> 6;
        int sc = s;
        #pragma unroll
        for (int off = 1; off < 64; off <<= 1) {
            int v = __shfl_up(sc, off, 64);
            if (lane >= off) sc += v;
        }
        if (lane == 63) wsum[wv] = sc;
        __syncthreads();
        if (t == 0) {
            int a = 0;
            #pragma unroll
            for (int w = 0; w < 4; ++w) { int v = wsum[w]; wsum[w] = a; a += v; }
        }
        __syncthreads();
        int run = wsum[wv] + sc - s;
        #pragma unroll
        for (int j = 0; j < KEYS / 256; ++j) {
            unsigned v = cnt[kbase + j];
            unsigned lc = v > 1023u ? 1023u : v;
            cnt[kbase + j] = (unsigned)run | (lc << 20);
            run += (int)v;
        }
        __syncthreads();
        {
            int d = b * 256 + t;
            if (d < N_NODES) {
                int rs = (int)(cnt[t * 32] & 0xFFFFFu);
                int re = (t < 255) ? (int)(cnt[(t + 1) * 32] & 0xFFFFFu) : cntE;
                rse[d] = make_int2((int)e0 + rs, (int)e0 + re);
            }
        }
        __syncthreads();
        for (int i = t; i < cntE; i += 256) {
            unsigned pk = ebuf[e0 + i];
            int key = pk >> 17;
            unsigned vv = atomicAdd(&cnt[key], 1u);
            int pos = (int)(vv & 0xFFFFFu);
            unsigned len = (vv >> 20) & 1023u;
            elist[e0 + pos] = (pk & 0x3FFFFFu) | (len << 22);
        }
    } else {
        // ---- A-stationary GEMM: stage 64x128 A (f32->bf16) once, loop 4 col-tiles ----
        unsigned short* As = (unsigned short*)smem;            // 64*136*2  = 17408
        unsigned short* Bs = (unsigned short*)(smem + 17408);  // 128*136*2 = 34816
        int row0 = (b - NBUCK) * 64;
        #pragma unroll
        for (int j = 0; j < 8; ++j) {
            int idx = t + j * 256;            // 0..2047 float4 units
            int r = idx >> 5;                 // 0..63
            int u = idx & 31;                 // float4 col unit
            int grow = row0 + r;
            float4 v = make_float4(0.f, 0.f, 0.f, 0.f);
            if (grow < N_NODES) v = *(const float4*)(A + (size_t)grow * F_IN + u * 4);
            ushort4 o;
            o.x = f2bf(v.x); o.y = f2bf(v.y); o.z = f2bf(v.z); o.w = f2bf(v.w);
            *(ushort4*)(&As[r * 136 + u * 4]) = o;
        }
        int w = t >> 6;
        int lane = t & 63;
        int q = lane >> 4;
        int mr = lane & 15;
        const unsigned short* ap = &As[(w * 16 + mr) * 136 + q * 8];
        for (int col0 = 0; col0 < NOUT; col0 += 128) {
            __syncthreads();   // Bs free from previous iteration (covers As stage on first)
            #pragma unroll
            for (int j = 0; j < 8; ++j) {
                int idx = t + j * 256;            // 0..2047
                int r = idx >> 4;                 // 0..127
                int u = idx & 15;
                float4 v = *(const float4*)(BmT + (size_t)(col0 + r) * F_IN + u * 8);
                *(float4*)(&Bs[r * 136 + u * 8]) = v;
            }
            __syncthreads();
            f32x4 acc[8] = {};
            #pragma unroll
            for (int kk = 0; kk < 4; ++kk) {
                bf16x8 af = *(const bf16x8*)(ap + kk * 32);
                #pragma unroll
                for (int tt = 0; tt < 8; ++tt) {
                    bf16x8 bf = *(const bf16x8*)(&Bs[(tt * 16 + mr) * 136 + q * 8 + kk * 32]);
                    acc[tt] = __builtin_amdgcn_mfma_f32_16x16x32_bf16(af, bf, acc[tt], 0, 0, 0);
                }
            }
            #pragma unroll
            for (int tt = 0; tt < 8; ++tt) {
                #pragma unroll
                for (int j = 0; j < 4; ++j) {
                    int row = row0 + w * 16 + q * 4 + j;
                    C[(size_t)row * NOUT + col0 + tt * 16 + mr] = f2bf(acc[tt][j]);
                }
            }
        }
    }
}

// ============ gather1: 8 lanes/node, 4 B loads, 4-edge unroll, h f16 ============
__global__ __launch_bounds__(256) void k_gather1(const int2* __restrict__ rse,
                                                 const unsigned int* __restrict__ elist,
                                                 const unsigned short* __restrict__ xw1,
                                                 _Float16* __restrict__ h) {
    __shared__ float nlut[1024];
    int t = threadIdx.x;
    for (int j = t; j < 1024; j += 256) nlut[j] = 1.0f / (float)(j ? j : 1);
    __syncthreads();
    int g = t >> 3;            // node in block, 0..31
    int c = t & 7;             // channel pair: elems c*2, c*2+1
    int d = blockIdx.x * 32 + g;
    if (d >= N_NODES) return;
    int2 rr = rse[d];
    int i = rr.x, end = rr.y;
    float a0 = 0.f, a1 = 0.f, b0 = 0.f, b1 = 0.f;
    float c0 = 0.f, c1 = 0.f, e0 = 0.f, e1 = 0.f;
    for (; i + 3 < end; i += 4) {
        unsigned pk0 = elist[i];
        unsigned pk1 = elist[i + 1];
        unsigned pk2 = elist[i + 2];
        unsigned pk3 = elist[i + 3];
        unsigned x0 = *(const unsigned*)(xw1 + (size_t)(pk0 & 0x1FFFF) * NOUT + ((pk0 >> 17) & 31) * HDIM + c * 2);
        unsigned x1 = *(const unsigned*)(xw1 + (size_t)(pk1 & 0x1FFFF) * NOUT + ((pk1 >> 17) & 31) * HDIM + c * 2);
        unsigned x2 = *(const unsigned*)(xw1 + (size_t)(pk2 & 0x1FFFF) * NOUT + ((pk2 >> 17) & 31) * HDIM + c * 2);
        unsigned x3 = *(const unsigned*)(xw1 + (size_t)(pk3 & 0x1FFFF) * NOUT + ((pk3 >> 17) & 31) * HDIM + c * 2);
        float n0 = nlut[pk0 >> 22], n1 = nlut[pk1 >> 22];
        float n2 = nlut[pk2 >> 22], n3 = nlut[pk3 >> 22];
        a0 += bfl(x0) * n0; a1 += bfh(x0) * n0;
        b0 += bfl(x1) * n1; b1 += bfh(x1) * n1;
        c0 += bfl(x2) * n2; c1 += bfh(x2) * n2;
        e0 += bfl(x3) * n3; e1 += bfh(x3) * n3;
    }
    for (; i < end; ++i) {
        unsigned pk = elist[i];
        unsigned x = *(const unsigned*)(xw1 + (size_t)(pk & 0x1FFFF) * NOUT + ((pk >> 17) & 31) * HDIM + c * 2);
        float nm = nlut[pk >> 22];
        a0 += bfl(x) * nm; a1 += bfh(x) * nm;
    }
    f16x2 o;
    o.x = (_Float16)fmaxf(a0 + b0 + c0 + e0, 0.f);
    o.y = (_Float16)fmaxf(a1 + b1 + c1 + e1, 0.f);
    *(f16x2*)(h + (size_t)d * HDIM + c * 2) = o;
}

// ============ gather2: run-level aggregate-then-transform + fused log_softmax ============
// lane c of 8 holds h channels (2c,2c+1); per run: shfl all-gather + 8 FDOT2
__global__ __launch_bounds__(256) void k_gather2(const int2* __restrict__ rse,
                                                 const unsigned int* __restrict__ elist,
                                                 const _Float16* __restrict__ h,
                                                 const float* __restrict__ W2,
                                                 float* __restrict__ out) {
    __shared__ f16x2 w2t[64 * 33];   // (k*8+c)*33 + r : (W2[r][2k][c], W2[r][2k+1][c])
    __shared__ float nlut[1024];
    int t = threadIdx.x;
    for (int j = t; j < 1024; j += 256) nlut[j] = 1.0f / (float)(j ? j : 1);
    #pragma unroll
    for (int j = 0; j < 8; ++j) {
        int idx = t + j * 256;           // 0..2047
        int k = idx >> 8;                // 0..7
        int c = (idx >> 5) & 7;
        int r = idx & 31;
        f16x2 p;
        p.x = (_Float16)W2[r * 128 + (2 * k) * 8 + c];
        p.y = (_Float16)W2[r * 128 + (2 * k + 1) * 8 + c];
        w2t[(k * 8 + c) * 33 + r] = p;
    }
    __syncthreads();

    int g = t >> 3;
    int c = t & 7;
    int d = blockIdx.x * 32 + g;
    if (d >= N_NODES) return;
    int2 rr = rse[d];
    int i = rr.x, end = rr.y;
    float acc = 0.f;
    while (i < end) {
        unsigned pk = elist[i];
        int r = (pk >> 17) & 31;
        int len = pk >> 22;
        float nm = nlut[len];
        int stop = i + len;
        f16x2 hs = {(_Float16)0.f, (_Float16)0.f};
        for (; i < stop; ++i) {
            int s = elist[i] & 0x1FFFF;
            hs += *(const f16x2*)(h + (size_t)s * HDIM + c * 2);
        }
        float hvf = asflt(hs);
        float runsum = 0.f;
        #pragma unroll
        for (int k = 0; k < 8; ++k) {
            float hvk = __shfl(hvf, k, 8);
            runsum = FDOT2(asf16x2(hvk), w2t[(k * 8 + c) * 33 + r], runsum);
        }
        acc += nm * runsum;
    }
    float m = acc;
    #pragma unroll
    for (int mask = 1; mask < 8; mask <<= 1)
        m = fmaxf(m, __shfl_xor(m, mask, 8));
    float ex = expf(acc - m);
    float ssumv = ex;
    #pragma unroll
    for (int mask = 1; mask < 8; mask <<= 1)
        ssumv += __shfl_xor(ssumv, mask, 8);
    out[(size_t)d * CDIM + c] = acc - m - logf(ssumv);
}

extern "C" void kernel_launch(void* const* d_in, const int* in_sizes, int n_in,
                              void* d_out, int out_size, void* d_ws, size_t ws_size,
                              hipStream_t stream) {
    const float* emb = (const float*)d_in[0];
    const float* W1  = (const float*)d_in[1];
    const float* W2  = (const float*)d_in[2];
    const int* ei    = (const int*)d_in[3];
    const int* et    = (const int*)d_in[4];
    const int* srcp  = ei;
    const int* dstp  = ei + E_EDGES;

    char* ws = (char*)d_ws;
    size_t off = 0;
    #define ALIGN256(x) (((x) + 255) & ~(size_t)255)
    int* gcursor     = (int*)(ws + off); off = ALIGN256(off + 512 * 4);
    int2* rse        = (int2*)(ws + off); off = ALIGN256(off + ((size_t)N_NODES + 8) * 8);
    unsigned int* ebuf  = (unsigned int*)(ws + off); off = ALIGN256(off + (size_t)NBUCK * CAP * 4);
    unsigned int* elist = (unsigned int*)(ws + off); off = ALIGN256(off + (size_t)NBUCK * CAP * 4);
    unsigned short* BmT  = (unsigned short*)(ws + off); off = ALIGN256(off + (size_t)NOUT * F_IN * 2);
    unsigned short* xw1  = (unsigned short*)(ws + off); off = ALIGN256(off + (size_t)M_PAD * NOUT * 2);
    _Float16* h          = (_Float16*)(ws + off);       off = ALIGN256(off + (size_t)N_NODES * HDIM * 2);
    float* out = (float*)d_out;

    hipMemsetAsync(gcursor, 0, 512 * 4, stream);

    k_front<<<FRONT_GRID, 512, 0, stream>>>(srcp, dstp, et, W1, gcursor, ebuf, BmT);
    k_mid<<<MID_GRID, 256, 0, stream>>>(ebuf, gcursor, rse, elist, emb, BmT, xw1);
    k_gather1<<<(N_NODES + 31) / 32, 256, 0, stream>>>(rse, elist, xw1, h);
    k_gather2<<<(N_NODES + 31) / 32, 256, 0, stream>>>(rse, elist, h, W2, out);
}

// Round 9
// 363.017 us; speedup vs baseline: 1.0784x; 1.0784x over previous
//
#include <hip/hip_runtime.h>
#include <hip/hip_bf16.h>
#include <math.h>

#define N_NODES 100000
#define R 32
#define E_EDGES 3200000
#define F_IN 128
#define HDIM 16
#define CDIM 8
#define NOUT 512               // R * HDIM
#define M_PAD 100032           // 1563 * 64
#define NBUCK 391              // ceil(N_NODES / 256)
#define CAP 9216               // bucket capacity: mean 8184, +11.4 sigma
#define KEYS 8192              // 256 nodes * 32 rels per bucket
#define P1CHUNK 2048           // small chunks -> 1563 scatter blocks (occupancy)
#define NCHK ((E_EDGES + P1CHUNK - 1) / P1CHUNK)     // 1563
#define PREP_BLKS 256          // NOUT*F_IN / 256
#define FRONT_GRID (NCHK + PREP_BLKS)
#define GEMM_BLKS 1563         // M_PAD/64  (A-stationary: col loop inside)
#define MID_GRID (NBUCK + GEMM_BLKS)

typedef __attribute__((ext_vector_type(8))) short bf16x8;
typedef __attribute__((ext_vector_type(4))) float f32x4;
typedef __attribute__((ext_vector_type(2))) _Float16 f16x2;

static __device__ __forceinline__ unsigned short f2bf(float f) {
    unsigned int u = __float_as_uint(f);
    unsigned int r = (u + 0x7FFFu + ((u >> 16) & 1u)) >> 16;
    return (unsigned short)r;
}
static __device__ __forceinline__ float bfl(unsigned x) {
    return __uint_as_float(x << 16);
}
static __device__ __forceinline__ float bfh(unsigned x) {
    return __uint_as_float(x & 0xFFFF0000u);
}
static __device__ __forceinline__ f16x2 asf16x2(float f) {
    union { float f; f16x2 h; } u; u.f = f; return u.h;
}

#if __has_builtin(__builtin_amdgcn_fdot2)
static __device__ __forceinline__ float FDOT2(f16x2 a, f16x2 b, float c) {
    return __builtin_amdgcn_fdot2(a, b, c, false);
}
#else
static __device__ __forceinline__ float FDOT2(f16x2 a, f16x2 b, float c) {
    return c + (float)a.x * (float)b.x + (float)a.y * (float)b.y;
}
#endif

// ============ k_front: bucket-scatter (2048-edge chunks) ∥ W1 repack ============
// packed ebuf entry: dl(8b)<<22 | et(5b)<<17 | src(17b)
__global__ __launch_bounds__(256) void k_front(const int* __restrict__ src,
                                               const int* __restrict__ dst,
                                               const int* __restrict__ et,
                                               const float* __restrict__ W1,
                                               int* __restrict__ gcursor,
                                               unsigned int* __restrict__ ebuf,
                                               unsigned short* __restrict__ BmT) {
    __shared__ int sh[3 * NBUCK];
    int b = blockIdx.x, t = threadIdx.x;
    if (b < NCHK) {
        int* hist = sh;
        int* rank = sh + NBUCK;
        int* base = sh + 2 * NBUCK;
        for (int j = t; j < NBUCK; j += 256) { hist[j] = 0; rank[j] = 0; }
        __syncthreads();
        int e0 = b * P1CHUNK;
        int e1 = e0 + P1CHUNK; if (e1 > E_EDGES) e1 = E_EDGES;
        int n4 = (e1 - e0) >> 2;
        const int4* d4 = (const int4*)(dst + e0);
        const int4* s4 = (const int4*)(src + e0);
        const int4* t4 = (const int4*)(et + e0);
        for (int i = t; i < n4; i += 256) {
            int4 v = d4[i];
            atomicAdd(&hist[v.x >> 8], 1);
            atomicAdd(&hist[v.y >> 8], 1);
            atomicAdd(&hist[v.z >> 8], 1);
            atomicAdd(&hist[v.w >> 8], 1);
        }
        __syncthreads();
        for (int j = t; j < NBUCK; j += 256)
            base[j] = hist[j] ? atomicAdd(&gcursor[j], hist[j]) : 0;
        __syncthreads();
        for (int i = t; i < n4; i += 256) {
            int4 dv = d4[i];
            int4 sv = s4[i];
            int4 tv = t4[i];
            int ds[4] = {dv.x, dv.y, dv.z, dv.w};
            int ss[4] = {sv.x, sv.y, sv.z, sv.w};
            int ts[4] = {tv.x, tv.y, tv.z, tv.w};
            #pragma unroll
            for (int u = 0; u < 4; ++u) {
                int d = ds[u];
                int bk = d >> 8;
                unsigned pk = ((unsigned)(d & 255) << 22) | ((unsigned)ts[u] << 17)
                            | (unsigned)ss[u];
                int lr = atomicAdd(&rank[bk], 1);
                ebuf[(size_t)bk * CAP + base[bk] + lr] = pk;
            }
        }
    } else {
        // W1 [R,128,16] -> BmT bf16 [512][128] (n=r*16+o, k=f)
        int i = (b - NCHK) * 256 + t;
        int n = i >> 7;
        int f = i & 127;
        int r = n >> 4;
        int o = n & 15;
        BmT[i] = f2bf(W1[r * (F_IN * HDIM) + f * HDIM + o]);
    }
}

// ============ k_mid: per-bucket counting sort ∥ A-stationary MFMA GEMM ============
// final elist entry: len(10b)<<22 | et(5b)<<17 | src(17b); fixed bucket base b*CAP
__global__ __launch_bounds__(256) void k_mid(const unsigned int* __restrict__ ebuf,
                                             const int* __restrict__ gcursor,
                                             int2* __restrict__ rse,
                                             unsigned int* __restrict__ elist,
                                             const float* __restrict__ A,
                                             const unsigned short* __restrict__ BmT,
                                             unsigned short* __restrict__ C) {
    __shared__ __align__(16) char smem[52224 + 64];
    int b = blockIdx.x, t = threadIdx.x;
    if (b < NBUCK) {
        // ---- counting sort, 256 threads ----
        unsigned int* cnt = (unsigned int*)smem;       // 8192 * 4 = 32 KB
        int* wsum = (int*)(smem + 32768);              // 4 ints
        int cntE = gcursor[b];
        size_t e0 = (size_t)b * CAP;
        #pragma unroll
        for (int j = 0; j < KEYS / 256; ++j) cnt[t + j * 256] = 0;
        __syncthreads();
        for (int i = t; i < cntE; i += 256)
            atomicAdd(&cnt[ebuf[e0 + i] >> 17], 1u);   // key = dl*32 + et
        __syncthreads();
        int kbase = t * (KEYS / 256);
        int s = 0;
        #pragma unroll
        for (int j = 0; j < KEYS / 256; ++j) s += (int)cnt[kbase + j];
        int lane = t & 63, wv = t >> 6;
        int sc = s;
        #pragma unroll
        for (int off = 1; off < 64; off <<= 1) {
            int v = __shfl_up(sc, off, 64);
            if (lane >= off) sc += v;
        }
        if (lane == 63) wsum[wv] = sc;
        __syncthreads();
        if (t == 0) {
            int a = 0;
            #pragma unroll
            for (int w = 0; w < 4; ++w) { int v = wsum[w]; wsum[w] = a; a += v; }
        }
        __syncthreads();
        int run = wsum[wv] + sc - s;
        #pragma unroll
        for (int j = 0; j < KEYS / 256; ++j) {
            unsigned v = cnt[kbase + j];
            unsigned lc = v > 1023u ? 1023u : v;
            cnt[kbase + j] = (unsigned)run | (lc << 20);
            run += (int)v;
        }
        __syncthreads();
        {
            int d = b * 256 + t;
            if (d < N_NODES) {
                int rs = (int)(cnt[t * 32] & 0xFFFFFu);
                int re = (t < 255) ? (int)(cnt[(t + 1) * 32] & 0xFFFFFu) : cntE;
                rse[d] = make_int2((int)e0 + rs, (int)e0 + re);
            }
        }
        __syncthreads();
        for (int i = t; i < cntE; i += 256) {
            unsigned pk = ebuf[e0 + i];
            int key = pk >> 17;
            unsigned vv = atomicAdd(&cnt[key], 1u);
            int pos = (int)(vv & 0xFFFFFu);
            unsigned len = (vv >> 20) & 1023u;
            elist[e0 + pos] = (pk & 0x3FFFFFu) | (len << 22);
        }
    } else {
        // ---- A-stationary GEMM: stage 64x128 A (f32->bf16) once, loop 4 col-tiles ----
        unsigned short* As = (unsigned short*)smem;            // 64*136*2  = 17408
        unsigned short* Bs = (unsigned short*)(smem + 17408);  // 128*136*2 = 34816
        int row0 = (b - NBUCK) * 64;
        #pragma unroll
        for (int j = 0; j < 8; ++j) {
            int idx = t + j * 256;            // 0..2047 float4 units
            int r = idx >> 5;                 // 0..63
            int u = idx & 31;                 // float4 col unit
            int grow = row0 + r;
            float4 v = make_float4(0.f, 0.f, 0.f, 0.f);
            if (grow < N_NODES) v = *(const float4*)(A + (size_t)grow * F_IN + u * 4);
            ushort4 o;
            o.x = f2bf(v.x); o.y = f2bf(v.y); o.z = f2bf(v.z); o.w = f2bf(v.w);
            *(ushort4*)(&As[r * 136 + u * 4]) = o;
        }
        int w = t >> 6;
        int lane = t & 63;
        int q = lane >> 4;
        int mr = lane & 15;
        const unsigned short* ap = &As[(w * 16 + mr) * 136 + q * 8];
        for (int col0 = 0; col0 < NOUT; col0 += 128) {
            __syncthreads();   // Bs free from previous iteration (covers As stage on first)
            #pragma unroll
            for (int j = 0; j < 8; ++j) {
                int idx = t + j * 256;            // 0..2047
                int r = idx >> 4;                 // 0..127
                int u = idx & 15;
                float4 v = *(const float4*)(BmT + (size_t)(col0 + r) * F_IN + u * 8);
                *(float4*)(&Bs[r * 136 + u * 8]) = v;
            }
            __syncthreads();
            f32x4 acc[8] = {};
            #pragma unroll
            for (int kk = 0; kk < 4; ++kk) {
                bf16x8 af = *(const bf16x8*)(ap + kk * 32);
                #pragma unroll
                for (int tt = 0; tt < 8; ++tt) {
                    bf16x8 bf = *(const bf16x8*)(&Bs[(tt * 16 + mr) * 136 + q * 8 + kk * 32]);
                    acc[tt] = __builtin_amdgcn_mfma_f32_16x16x32_bf16(af, bf, acc[tt], 0, 0, 0);
                }
            }
            #pragma unroll
            for (int tt = 0; tt < 8; ++tt) {
                #pragma unroll
                for (int j = 0; j < 4; ++j) {
                    int row = row0 + w * 16 + q * 4 + j;
                    C[(size_t)row * NOUT + col0 + tt * 16 + mr] = f2bf(acc[tt][j]);
                }
            }
        }
    }
}

// ============ gather1: 8 lanes/node, 4 B loads, 4-edge unroll, h f16 ============
__global__ __launch_bounds__(256) void k_gather1(const int2* __restrict__ rse,
                                                 const unsigned int* __restrict__ elist,
                                                 const unsigned short* __restrict__ xw1,
                                                 _Float16* __restrict__ h) {
    __shared__ float nlut[1024];
    int t = threadIdx.x;
    for (int j = t; j < 1024; j += 256) nlut[j] = 1.0f / (float)(j ? j : 1);
    __syncthreads();
    int g = t >> 3;            // node in block, 0..31
    int c = t & 7;             // channel pair: elems c*2, c*2+1
    int d = blockIdx.x * 32 + g;
    if (d >= N_NODES) return;
    int2 rr = rse[d];
    int i = rr.x, end = rr.y;
    float a0 = 0.f, a1 = 0.f, b0 = 0.f, b1 = 0.f;
    float c0 = 0.f, c1 = 0.f, e0 = 0.f, e1 = 0.f;
    for (; i + 3 < end; i += 4) {
        unsigned pk0 = elist[i];
        unsigned pk1 = elist[i + 1];
        unsigned pk2 = elist[i + 2];
        unsigned pk3 = elist[i + 3];
        unsigned x0 = *(const unsigned*)(xw1 + (size_t)(pk0 & 0x1FFFF) * NOUT + ((pk0 >> 17) & 31) * HDIM + c * 2);
        unsigned x1 = *(const unsigned*)(xw1 + (size_t)(pk1 & 0x1FFFF) * NOUT + ((pk1 >> 17) & 31) * HDIM + c * 2);
        unsigned x2 = *(const unsigned*)(xw1 + (size_t)(pk2 & 0x1FFFF) * NOUT + ((pk2 >> 17) & 31) * HDIM + c * 2);
        unsigned x3 = *(const unsigned*)(xw1 + (size_t)(pk3 & 0x1FFFF) * NOUT + ((pk3 >> 17) & 31) * HDIM + c * 2);
        float n0 = nlut[pk0 >> 22], n1 = nlut[pk1 >> 22];
        float n2 = nlut[pk2 >> 22], n3 = nlut[pk3 >> 22];
        a0 += bfl(x0) * n0; a1 += bfh(x0) * n0;
        b0 += bfl(x1) * n1; b1 += bfh(x1) * n1;
        c0 += bfl(x2) * n2; c1 += bfh(x2) * n2;
        e0 += bfl(x3) * n3; e1 += bfh(x3) * n3;
    }
    for (; i < end; ++i) {
        unsigned pk = elist[i];
        unsigned x = *(const unsigned*)(xw1 + (size_t)(pk & 0x1FFFF) * NOUT + ((pk >> 17) & 31) * HDIM + c * 2);
        float nm = nlut[pk >> 22];
        a0 += bfl(x) * nm; a1 += bfh(x) * nm;
    }
    f16x2 o;
    o.x = (_Float16)fmaxf(a0 + b0 + c0 + e0, 0.f);
    o.y = (_Float16)fmaxf(a1 + b1 + c1 + e1, 0.f);
    *(f16x2*)(h + (size_t)d * HDIM + c * 2) = o;
}

// ============ gather2 + fused log_softmax: 8 lanes/node, dot2, 4-edge unroll ============
#define W2P 260   // per-class stride in f16x2 units
__global__ __launch_bounds__(256) void k_gather2(const int2* __restrict__ rse,
                                                 const unsigned int* __restrict__ elist,
                                                 const _Float16* __restrict__ h,
                                                 const float* __restrict__ W2,
                                                 float* __restrict__ out) {
    __shared__ f16x2 sW2h[CDIM * W2P];
    __shared__ float nlut[1024];
    int t = threadIdx.x;
    for (int j = t; j < 1024; j += 256) nlut[j] = 1.0f / (float)(j ? j : 1);
    #pragma unroll
    for (int j = 0; j < 8; ++j) {
        int idx = t + j * 256;           // 0..2047
        int c = idx >> 8;
        int rem = idx & 255;             // r*8 + jj
        int r = rem >> 3;
        int jj = rem & 7;
        f16x2 p;
        p.x = (_Float16)W2[r * (HDIM * CDIM) + (2 * jj) * CDIM + c];
        p.y = (_Float16)W2[r * (HDIM * CDIM) + (2 * jj + 1) * CDIM + c];
        sW2h[c * W2P + rem] = p;
    }
    __syncthreads();

    int g = t >> 3;
    int c = t & 7;
    int d = blockIdx.x * 32 + g;
    if (d >= N_NODES) return;
    const f16x2* wc = &sW2h[c * W2P];
    int2 rr = rse[d];
    int i = rr.x, end = rr.y;
    float acc0 = 0.f, acc1 = 0.f, acc2 = 0.f, acc3 = 0.f;
    for (; i + 3 < end; i += 4) {
        unsigned pk0 = elist[i];
        unsigned pk1 = elist[i + 1];
        unsigned pk2 = elist[i + 2];
        unsigned pk3 = elist[i + 3];
        const float4* hp0 = (const float4*)(h + (size_t)(pk0 & 0x1FFFF) * HDIM);
        const float4* hp1 = (const float4*)(h + (size_t)(pk1 & 0x1FFFF) * HDIM);
        const float4* hp2 = (const float4*)(h + (size_t)(pk2 & 0x1FFFF) * HDIM);
        const float4* hp3 = (const float4*)(h + (size_t)(pk3 & 0x1FFFF) * HDIM);
        float4 u0 = hp0[0], u1 = hp0[1];
        float4 v0 = hp1[0], v1 = hp1[1];
        float4 w0 = hp2[0], w1 = hp2[1];
        float4 x0 = hp3[0], x1 = hp3[1];
        float nm0 = nlut[pk0 >> 22], nm1 = nlut[pk1 >> 22];
        float nm2 = nlut[pk2 >> 22], nm3 = nlut[pk3 >> 22];
        const f16x2* wp0 = wc + ((pk0 >> 17) & 31) * 8;
        const f16x2* wp1 = wc + ((pk1 >> 17) & 31) * 8;
        const f16x2* wp2 = wc + ((pk2 >> 17) & 31) * 8;
        const f16x2* wp3 = wc + ((pk3 >> 17) & 31) * 8;
        float s0 = 0.f, s1 = 0.f, s2 = 0.f, s3 = 0.f;
        s0 = FDOT2(asf16x2(u0.x), wp0[0], s0);
        s0 = FDOT2(asf16x2(u0.y), wp0[1], s0);
        s0 = FDOT2(asf16x2(u0.z), wp0[2], s0);
        s0 = FDOT2(asf16x2(u0.w), wp0[3], s0);
        s0 = FDOT2(asf16x2(u1.x), wp0[4], s0);
        s0 = FDOT2(asf16x2(u1.y), wp0[5], s0);
        s0 = FDOT2(asf16x2(u1.z), wp0[6], s0);
        s0 = FDOT2(asf16x2(u1.w), wp0[7], s0);
        s1 = FDOT2(asf16x2(v0.x), wp1[0], s1);
        s1 = FDOT2(asf16x2(v0.y), wp1[1], s1);
        s1 = FDOT2(asf16x2(v0.z), wp1[2], s1);
        s1 = FDOT2(asf16x2(v0.w), wp1[3], s1);
        s1 = FDOT2(asf16x2(v1.x), wp1[4], s1);
        s1 = FDOT2(asf16x2(v1.y), wp1[5], s1);
        s1 = FDOT2(asf16x2(v1.z), wp1[6], s1);
        s1 = FDOT2(asf16x2(v1.w), wp1[7], s1);
        s2 = FDOT2(asf16x2(w0.x), wp2[0], s2);
        s2 = FDOT2(asf16x2(w0.y), wp2[1], s2);
        s2 = FDOT2(asf16x2(w0.z), wp2[2], s2);
        s2 = FDOT2(asf16x2(w0.w), wp2[3], s2);
        s2 = FDOT2(asf16x2(w1.x), wp2[4], s2);
        s2 = FDOT2(asf16x2(w1.y), wp2[5], s2);
        s2 = FDOT2(asf16x2(w1.z), wp2[6], s2);
        s2 = FDOT2(asf16x2(w1.w), wp2[7], s2);
        s3 = FDOT2(asf16x2(x0.x), wp3[0], s3);
        s3 = FDOT2(asf16x2(x0.y), wp3[1], s3);
        s3 = FDOT2(asf16x2(x0.z), wp3[2], s3);
        s3 = FDOT2(asf16x2(x0.w), wp3[3], s3);
        s3 = FDOT2(asf16x2(x1.x), wp3[4], s3);
        s3 = FDOT2(asf16x2(x1.y), wp3[5], s3);
        s3 = FDOT2(asf16x2(x1.z), wp3[6], s3);
        s3 = FDOT2(asf16x2(x1.w), wp3[7], s3);
        acc0 += nm0 * s0;
        acc1 += nm1 * s1;
        acc2 += nm2 * s2;
        acc3 += nm3 * s3;
    }
    for (; i < end; ++i) {
        unsigned pk = elist[i];
        const float4* hp = (const float4*)(h + (size_t)(pk & 0x1FFFF) * HDIM);
        float4 u0 = hp[0], u1 = hp[1];
        float nm = nlut[pk >> 22];
        const f16x2* wp = wc + ((pk >> 17) & 31) * 8;
        float sd = 0.f;
        sd = FDOT2(asf16x2(u0.x), wp[0], sd);
        sd = FDOT2(asf16x2(u0.y), wp[1], sd);
        sd = FDOT2(asf16x2(u0.z), wp[2], sd);
        sd = FDOT2(asf16x2(u0.w), wp[3], sd);
        sd = FDOT2(asf16x2(u1.x), wp[4], sd);
        sd = FDOT2(asf16x2(u1.y), wp[5], sd);
        sd = FDOT2(asf16x2(u1.z), wp[6], sd);
        sd = FDOT2(asf16x2(u1.w), wp[7], sd);
        acc0 += nm * sd;
    }
    float acc = (acc0 + acc1) + (acc2 + acc3);
    float m = acc;
    #pragma unroll
    for (int mask = 1; mask < 8; mask <<= 1)
        m = fmaxf(m, __shfl_xor(m, mask, 8));
    float ex = expf(acc - m);
    float ssumv = ex;
    #pragma unroll
    for (int mask = 1; mask < 8; mask <<= 1)
        ssumv += __shfl_xor(ssumv, mask, 8);
    out[(size_t)d * CDIM + c] = acc - m - logf(ssumv);
}

extern "C" void kernel_launch(void* const* d_in, const int* in_sizes, int n_in,
                              void* d_out, int out_size, void* d_ws, size_t ws_size,
                              hipStream_t stream) {
    const float* emb = (const float*)d_in[0];
    const float* W1  = (const float*)d_in[1];
    const float* W2  = (const float*)d_in[2];
    const int* ei    = (const int*)d_in[3];
    const int* et    = (const int*)d_in[4];
    const int* srcp  = ei;
    const int* dstp  = ei + E_EDGES;

    char* ws = (char*)d_ws;
    size_t off = 0;
    #define ALIGN256(x) (((x) + 255) & ~(size_t)255)
    int* gcursor     = (int*)(ws + off); off = ALIGN256(off + 512 * 4);
    int2* rse        = (int2*)(ws + off); off = ALIGN256(off + ((size_t)N_NODES + 8) * 8);
    unsigned int* ebuf  = (unsigned int*)(ws + off); off = ALIGN256(off + (size_t)NBUCK * CAP * 4);
    unsigned int* elist = (unsigned int*)(ws + off); off = ALIGN256(off + (size_t)NBUCK * CAP * 4);
    unsigned short* BmT  = (unsigned short*)(ws + off); off = ALIGN256(off + (size_t)NOUT * F_IN * 2);
    unsigned short* xw1  = (unsigned short*)(ws + off); off = ALIGN256(off + (size_t)M_PAD * NOUT * 2);
    _Float16* h          = (_Float16*)(ws + off);       off = ALIGN256(off + (size_t)N_NODES * HDIM * 2);
    float* out = (float*)d_out;

    hipMemsetAsync(gcursor, 0, 512 * 4, stream);

    k_front<<<FRONT_GRID, 256, 0, stream>>>(srcp, dstp, et, W1, gcursor, ebuf, BmT);
    k_mid<<<MID_GRID, 256, 0, stream>>>(ebuf, gcursor, rse, elist, emb, BmT, xw1);
    k_gather1<<<(N_NODES + 31) / 32, 256, 0, stream>>>(rse, elist, xw1, h);
    k_gather2<<<(N_NODES + 31) / 32, 256, 0, stream>>>(rse, elist, h, W2, out);
}

// Round 10
// 327.976 us; speedup vs baseline: 1.1936x; 1.1068x over previous
//
#include <hip/hip_runtime.h>
#include <hip/hip_bf16.h>
#include <math.h>

#define N_NODES 100000
#define R 32
#define E_EDGES 3200000
#define F_IN 128
#define HDIM 16
#define CDIM 8
#define NOUT 512               // R * HDIM
#define M_PAD 100032           // 1563 * 64
#define NBUCK 391              // ceil(N_NODES / 256)
#define CAP 9216               // bucket capacity: mean 8184, +11.4 sigma
#define KEYS 8192              // 256 nodes * 32 rels per bucket
#define P1CHUNK 8192
#define CVT_BLKS 6252          // M_PAD*F_IN/4 / 512
#define PREP_BLKS 128          // NOUT*F_IN / 512
#define FRONT_GRID (NBUCK + CVT_BLKS + PREP_BLKS)
#define GEMM_BLKS 1563         // M_PAD/64  (A-stationary: col loop inside)
#define MID_GRID (NBUCK + GEMM_BLKS)

typedef __attribute__((ext_vector_type(8))) short bf16x8;
typedef __attribute__((ext_vector_type(4))) float f32x4;
typedef __attribute__((ext_vector_type(2))) _Float16 f16x2;

static __device__ __forceinline__ unsigned short f2bf(float f) {
    unsigned int u = __float_as_uint(f);
    unsigned int r = (u + 0x7FFFu + ((u >> 16) & 1u)) >> 16;
    return (unsigned short)r;
}
static __device__ __forceinline__ float bfl(unsigned x) {
    return __uint_as_float(x << 16);
}
static __device__ __forceinline__ float bfh(unsigned x) {
    return __uint_as_float(x & 0xFFFF0000u);
}
static __device__ __forceinline__ f16x2 asf16x2(float f) {
    union { float f; f16x2 h; } u; u.f = f; return u.h;
}

#if __has_builtin(__builtin_amdgcn_fdot2)
static __device__ __forceinline__ float FDOT2(f16x2 a, f16x2 b, float c) {
    return __builtin_amdgcn_fdot2(a, b, c, false);
}
#else
static __device__ __forceinline__ float FDOT2(f16x2 a, f16x2 b, float c) {
    return c + (float)a.x * (float)b.x + (float)a.y * (float)b.y;
}
#endif

// ============ k_front: bucket-scatter ∥ emb->bf16 cvt ∥ W1 repack ============
// packed ebuf entry: dl(8b)<<22 | et(5b)<<17 | src(17b)
__global__ __launch_bounds__(512) void k_front(const int* __restrict__ src,
                                               const int* __restrict__ dst,
                                               const int* __restrict__ et,
                                               const float* __restrict__ emb,
                                               const float* __restrict__ W1,
                                               int* __restrict__ gcursor,
                                               unsigned int* __restrict__ ebuf,
                                               unsigned short* __restrict__ ebf,
                                               unsigned short* __restrict__ BmT) {
    __shared__ int sh[3 * NBUCK];
    int b = blockIdx.x, t = threadIdx.x;
    if (b < NBUCK) {
        int* hist = sh;
        int* rank = sh + NBUCK;
        int* base = sh + 2 * NBUCK;
        for (int j = t; j < NBUCK; j += 512) { hist[j] = 0; rank[j] = 0; }
        __syncthreads();
        int e0 = b * P1CHUNK;
        int e1 = e0 + P1CHUNK; if (e1 > E_EDGES) e1 = E_EDGES;
        int n4 = (e1 - e0) >> 2;
        const int4* d4 = (const int4*)(dst + e0);
        const int4* s4 = (const int4*)(src + e0);
        const int4* t4 = (const int4*)(et + e0);
        for (int i = t; i < n4; i += 512) {
            int4 v = d4[i];
            atomicAdd(&hist[v.x >> 8], 1);
            atomicAdd(&hist[v.y >> 8], 1);
            atomicAdd(&hist[v.z >> 8], 1);
            atomicAdd(&hist[v.w >> 8], 1);
        }
        __syncthreads();
        for (int j = t; j < NBUCK; j += 512)
            base[j] = hist[j] ? atomicAdd(&gcursor[j], hist[j]) : 0;
        __syncthreads();
        for (int i = t; i < n4; i += 512) {
            int4 dv = d4[i];
            int4 sv = s4[i];
            int4 tv = t4[i];
            int ds[4] = {dv.x, dv.y, dv.z, dv.w};
            int ss[4] = {sv.x, sv.y, sv.z, sv.w};
            int ts[4] = {tv.x, tv.y, tv.z, tv.w};
            #pragma unroll
            for (int u = 0; u < 4; ++u) {
                int d = ds[u];
                int bk = d >> 8;
                unsigned pk = ((unsigned)(d & 255) << 22) | ((unsigned)ts[u] << 17)
                            | (unsigned)ss[u];
                int lr = atomicAdd(&rank[bk], 1);
                ebuf[(size_t)bk * CAP + base[bk] + lr] = pk;
            }
        }
    } else if (b < NBUCK + CVT_BLKS) {
        // emb f32 -> bf16, rows padded to M_PAD with zeros; 1 float4-unit/thread
        size_t base = ((size_t)(b - NBUCK) * 512 + t) * 4;
        int row = (int)(base >> 7);
        ushort4 o;
        if (row < N_NODES) {
            float4 a = *(const float4*)(emb + base);
            o.x = f2bf(a.x); o.y = f2bf(a.y); o.z = f2bf(a.z); o.w = f2bf(a.w);
        } else {
            o.x = o.y = o.z = o.w = 0;
        }
        *(ushort4*)(ebf + base) = o;
    } else {
        // W1 [R,128,16] -> BmT bf16 [512][128] (n=r*16+o, k=f)
        int i = (b - NBUCK - CVT_BLKS) * 512 + t;
        int n = i >> 7;
        int f = i & 127;
        int r = n >> 4;
        int o = n & 15;
        BmT[i] = f2bf(W1[r * (F_IN * HDIM) + f * HDIM + o]);
    }
}

// ============ k_scanb: exclusive scan of bucket counts ============
__global__ __launch_bounds__(512) void k_scanb(const int* __restrict__ gcursor,
                                               int* __restrict__ bucketstart,
                                               int* __restrict__ rowstart) {
    __shared__ int sb[NBUCK + 1];
    int t = threadIdx.x;
    if (t == 0) {
        int acc = 0;
        for (int b = 0; b < NBUCK; ++b) { int v = gcursor[b]; sb[b] = acc; acc += v; }
        sb[NBUCK] = acc;
        rowstart[N_NODES] = acc;   // == E_EDGES
    }
    __syncthreads();
    for (int j = t; j <= NBUCK; j += 512) bucketstart[j] = sb[j];
}

// ============ k_mid: per-bucket counting sort ∥ A-stationary MFMA GEMM ============
// final elist entry: len(10b)<<22 | et(5b)<<17 | src(17b)
__global__ __launch_bounds__(256) void k_mid(const unsigned int* __restrict__ ebuf,
                                             const int* __restrict__ gcursor,
                                             const int* __restrict__ bucketstart,
                                             int* __restrict__ rowstart,
                                             unsigned int* __restrict__ elist,
                                             const unsigned short* __restrict__ Abf,
                                             const unsigned short* __restrict__ BmT,
                                             unsigned short* __restrict__ C) {
    __shared__ __align__(16) char smem[52224 + 64];
    int b = blockIdx.x, t = threadIdx.x;
    if (b < NBUCK) {
        // ---- counting sort, 256 threads ----
        unsigned int* cnt = (unsigned int*)smem;       // 8192 * 4 = 32 KB
        int* wsum = (int*)(smem + 32768);              // 4 ints
        int cntE = gcursor[b];
        size_t esrc = (size_t)b * CAP;
        int e0 = bucketstart[b];
        #pragma unroll
        for (int j = 0; j < KEYS / 256; ++j) cnt[t + j * 256] = 0;
        __syncthreads();
        for (int i = t; i < cntE; i += 256)
            atomicAdd(&cnt[ebuf[esrc + i] >> 17], 1u);  // key = dl*32 + et
        __syncthreads();
        int kbase = t * (KEYS / 256);
        int s = 0;
        #pragma unroll
        for (int j = 0; j < KEYS / 256; ++j) s += (int)cnt[kbase + j];
        int lane = t & 63, wv = t >> 6;
        int sc = s;
        #pragma unroll
        for (int off = 1; off < 64; off <<= 1) {
            int v = __shfl_up(sc, off, 64);
            if (lane >= off) sc += v;
        }
        if (lane == 63) wsum[wv] = sc;
        __syncthreads();
        if (t == 0) {
            int a = 0;
            #pragma unroll
            for (int w = 0; w < 4; ++w) { int v = wsum[w]; wsum[w] = a; a += v; }
        }
        __syncthreads();
        int run = wsum[wv] + sc - s;
        #pragma unroll
        for (int j = 0; j < KEYS / 256; ++j) {
            unsigned v = cnt[kbase + j];
            unsigned lc = v > 1023u ? 1023u : v;
            cnt[kbase + j] = (unsigned)run | (lc << 20);
            run += (int)v;
        }
        __syncthreads();
        {
            int d = b * 256 + t;
            if (d < N_NODES) rowstart[d] = e0 + (int)(cnt[t * 32] & 0xFFFFFu);
        }
        __syncthreads();
        for (int i = t; i < cntE; i += 256) {
            unsigned pk = ebuf[esrc + i];
            int key = pk >> 17;
            unsigned vv = atomicAdd(&cnt[key], 1u);
            int pos = (int)(vv & 0xFFFFFu);
            unsigned len = (vv >> 20) & 1023u;
            elist[e0 + pos] = (pk & 0x3FFFFFu) | (len << 22);
        }
    } else {
        // ---- A-stationary GEMM: stage 64x128 A once, loop 4 col-tiles of B ----
        unsigned short* As = (unsigned short*)smem;            // 64*136*2  = 17408
        unsigned short* Bs = (unsigned short*)(smem + 17408);  // 128*136*2 = 34816
        int row0 = (b - NBUCK) * 64;
        #pragma unroll
        for (int j = 0; j < 4; ++j) {
            int idx = t + j * 256;            // 0..1023 8-elem units
            int r = idx >> 4;
            int u = idx & 15;
            float4 v = *(const float4*)(Abf + (size_t)(row0 + r) * F_IN + u * 8);
            *(float4*)(&As[r * 136 + u * 8]) = v;
        }
        int w = t >> 6;
        int lane = t & 63;
        int q = lane >> 4;
        int mr = lane & 15;
        const unsigned short* ap = &As[(w * 16 + mr) * 136 + q * 8];
        for (int col0 = 0; col0 < NOUT; col0 += 128) {
            __syncthreads();   // Bs free from previous iteration (also covers As stage on first)
            #pragma unroll
            for (int j = 0; j < 8; ++j) {
                int idx = t + j * 256;            // 0..2047
                int r = idx >> 4;                 // 0..127
                int u = idx & 15;
                float4 v = *(const float4*)(BmT + (size_t)(col0 + r) * F_IN + u * 8);
                *(float4*)(&Bs[r * 136 + u * 8]) = v;
            }
            __syncthreads();
            f32x4 acc[8] = {};
            #pragma unroll
            for (int kk = 0; kk < 4; ++kk) {
                bf16x8 af = *(const bf16x8*)(ap + kk * 32);
                #pragma unroll
                for (int tt = 0; tt < 8; ++tt) {
                    bf16x8 bf = *(const bf16x8*)(&Bs[(tt * 16 + mr) * 136 + q * 8 + kk * 32]);
                    acc[tt] = __builtin_amdgcn_mfma_f32_16x16x32_bf16(af, bf, acc[tt], 0, 0, 0);
                }
            }
            #pragma unroll
            for (int tt = 0; tt < 8; ++tt) {
                #pragma unroll
                for (int j = 0; j < 4; ++j) {
                    int row = row0 + w * 16 + q * 4 + j;
                    C[(size_t)row * NOUT + col0 + tt * 16 + mr] = f2bf(acc[tt][j]);
                }
            }
        }
    }
}

// ============ gather1: 8 lanes/node, 4 B loads, 4-edge unroll, h f16 ============
__global__ __launch_bounds__(256) void k_gather1(const int* __restrict__ rowstart,
                                                 const unsigned int* __restrict__ elist,
                                                 const unsigned short* __restrict__ xw1,
                                                 _Float16* __restrict__ h) {
    __shared__ float nlut[1024];
    int t = threadIdx.x;
    for (int j = t; j < 1024; j += 256) nlut[j] = 1.0f / (float)(j ? j : 1);
    __syncthreads();
    int g = t >> 3;            // node in block, 0..31
    int c = t & 7;             // channel pair: elems c*2, c*2+1
    int d = blockIdx.x * 32 + g;
    if (d >= N_NODES) return;
    int i = rowstart[d], end = rowstart[d + 1];
    float a0 = 0.f, a1 = 0.f, b0 = 0.f, b1 = 0.f;
    float c0 = 0.f, c1 = 0.f, e0 = 0.f, e1 = 0.f;
    for (; i + 3 < end; i += 4) {
        unsigned pk0 = elist[i];
        unsigned pk1 = elist[i + 1];
        unsigned pk2 = elist[i + 2];
        unsigned pk3 = elist[i + 3];
        unsigned x0 = *(const unsigned*)(xw1 + (size_t)(pk0 & 0x1FFFF) * NOUT + ((pk0 >> 17) & 31) * HDIM + c * 2);
        unsigned x1 = *(const unsigned*)(xw1 + (size_t)(pk1 & 0x1FFFF) * NOUT + ((pk1 >> 17) & 31) * HDIM + c * 2);
        unsigned x2 = *(const unsigned*)(xw1 + (size_t)(pk2 & 0x1FFFF) * NOUT + ((pk2 >> 17) & 31) * HDIM + c * 2);
        unsigned x3 = *(const unsigned*)(xw1 + (size_t)(pk3 & 0x1FFFF) * NOUT + ((pk3 >> 17) & 31) * HDIM + c * 2);
        float n0 = nlut[pk0 >> 22], n1 = nlut[pk1 >> 22];
        float n2 = nlut[pk2 >> 22], n3 = nlut[pk3 >> 22];
        a0 += bfl(x0) * n0; a1 += bfh(x0) * n0;
        b0 += bfl(x1) * n1; b1 += bfh(x1) * n1;
        c0 += bfl(x2) * n2; c1 += bfh(x2) * n2;
        e0 += bfl(x3) * n3; e1 += bfh(x3) * n3;
    }
    for (; i < end; ++i) {
        unsigned pk = elist[i];
        unsigned x = *(const unsigned*)(xw1 + (size_t)(pk & 0x1FFFF) * NOUT + ((pk >> 17) & 31) * HDIM + c * 2);
        float nm = nlut[pk >> 22];
        a0 += bfl(x) * nm; a1 += bfh(x) * nm;
    }
    f16x2 o;
    o.x = (_Float16)fmaxf(a0 + b0 + c0 + e0, 0.f);
    o.y = (_Float16)fmaxf(a1 + b1 + c1 + e1, 0.f);
    *(f16x2*)(h + (size_t)d * HDIM + c * 2) = o;
}

// ============ gather2 + fused log_softmax: 8 lanes/node, dot2, 4-edge unroll ============
#define W2P 260   // per-class stride in f16x2 units
__global__ __launch_bounds__(256) void k_gather2(const int* __restrict__ rowstart,
                                                 const unsigned int* __restrict__ elist,
                                                 const _Float16* __restrict__ h,
                                                 const float* __restrict__ W2,
                                                 float* __restrict__ out) {
    __shared__ f16x2 sW2h[CDIM * W2P];
    __shared__ float nlut[1024];
    int t = threadIdx.x;
    for (int j = t; j < 1024; j += 256) nlut[j] = 1.0f / (float)(j ? j : 1);
    #pragma unroll
    for (int j = 0; j < 8; ++j) {
        int idx = t + j * 256;           // 0..2047
        int c = idx >> 8;
        int rem = idx & 255;             // r*8 + jj
        int r = rem >> 3;
        int jj = rem & 7;
        f16x2 p;
        p.x = (_Float16)W2[r * (HDIM * CDIM) + (2 * jj) * CDIM + c];
        p.y = (_Float16)W2[r * (HDIM * CDIM) + (2 * jj + 1) * CDIM + c];
        sW2h[c * W2P + rem] = p;
    }
    __syncthreads();

    int g = t >> 3;
    int c = t & 7;
    int d = blockIdx.x * 32 + g;
    if (d >= N_NODES) return;
    const f16x2* wc = &sW2h[c * W2P];
    int i = rowstart[d], end = rowstart[d + 1];
    float acc0 = 0.f, acc1 = 0.f, acc2 = 0.f, acc3 = 0.f;
    for (; i + 3 < end; i += 4) {
        unsigned pk0 = elist[i];
        unsigned pk1 = elist[i + 1];
        unsigned pk2 = elist[i + 2];
        unsigned pk3 = elist[i + 3];
        const float4* hp0 = (const float4*)(h + (size_t)(pk0 & 0x1FFFF) * HDIM);
        const float4* hp1 = (const float4*)(h + (size_t)(pk1 & 0x1FFFF) * HDIM);
        const float4* hp2 = (const float4*)(h + (size_t)(pk2 & 0x1FFFF) * HDIM);
        const float4* hp3 = (const float4*)(h + (size_t)(pk3 & 0x1FFFF) * HDIM);
        float4 u0 = hp0[0], u1 = hp0[1];
        float4 v0 = hp1[0], v1 = hp1[1];
        float4 w0 = hp2[0], w1 = hp2[1];
        float4 x0 = hp3[0], x1 = hp3[1];
        float nm0 = nlut[pk0 >> 22], nm1 = nlut[pk1 >> 22];
        float nm2 = nlut[pk2 >> 22], nm3 = nlut[pk3 >> 22];
        const f16x2* wp0 = wc + ((pk0 >> 17) & 31) * 8;
        const f16x2* wp1 = wc + ((pk1 >> 17) & 31) * 8;
        const f16x2* wp2 = wc + ((pk2 >> 17) & 31) * 8;
        const f16x2* wp3 = wc + ((pk3 >> 17) & 31) * 8;
        float s0 = 0.f, s1 = 0.f, s2 = 0.f, s3 = 0.f;
        s0 = FDOT2(asf16x2(u0.x), wp0[0], s0);
        s0 = FDOT2(asf16x2(u0.y), wp0[1], s0);
        s0 = FDOT2(asf16x2(u0.z), wp0[2], s0);
        s0 = FDOT2(asf16x2(u0.w), wp0[3], s0);
        s0 = FDOT2(asf16x2(u1.x), wp0[4], s0);
        s0 = FDOT2(asf16x2(u1.y), wp0[5], s0);
        s0 = FDOT2(asf16x2(u1.z), wp0[6], s0);
        s0 = FDOT2(asf16x2(u1.w), wp0[7], s0);
        s1 = FDOT2(asf16x2(v0.x), wp1[0], s1);
        s1 = FDOT2(asf16x2(v0.y), wp1[1], s1);
        s1 = FDOT2(asf16x2(v0.z), wp1[2], s1);
        s1 = FDOT2(asf16x2(v0.w), wp1[3], s1);
        s1 = FDOT2(asf16x2(v1.x), wp1[4], s1);
        s1 = FDOT2(asf16x2(v1.y), wp1[5], s1);
        s1 = FDOT2(asf16x2(v1.z), wp1[6], s1);
        s1 = FDOT2(asf16x2(v1.w), wp1[7], s1);
        s2 = FDOT2(asf16x2(w0.x), wp2[0], s2);
        s2 = FDOT2(asf16x2(w0.y), wp2[1], s2);
        s2 = FDOT2(asf16x2(w0.z), wp2[2], s2);
        s2 = FDOT2(asf16x2(w0.w), wp2[3], s2);
        s2 = FDOT2(asf16x2(w1.x), wp2[4], s2);
        s2 = FDOT2(asf16x2(w1.y), wp2[5], s2);
        s2 = FDOT2(asf16x2(w1.z), wp2[6], s2);
        s2 = FDOT2(asf16x2(w1.w), wp2[7], s2);
        s3 = FDOT2(asf16x2(x0.x), wp3[0], s3);
        s3 = FDOT2(asf16x2(x0.y), wp3[1], s3);
        s3 = FDOT2(asf16x2(x0.z), wp3[2], s3);
        s3 = FDOT2(asf16x2(x0.w), wp3[3], s3);
        s3 = FDOT2(asf16x2(x1.x), wp3[4], s3);
        s3 = FDOT2(asf16x2(x1.y), wp3[5], s3);
        s3 = FDOT2(asf16x2(x1.z), wp3[6], s3);
        s3 = FDOT2(asf16x2(x1.w), wp3[7], s3);
        acc0 += nm0 * s0;
        acc1 += nm1 * s1;
        acc2 += nm2 * s2;
        acc3 += nm3 * s3;
    }
    for (; i < end; ++i) {
        unsigned pk = elist[i];
        const float4* hp = (const float4*)(h + (size_t)(pk & 0x1FFFF) * HDIM);
        float4 u0 = hp[0], u1 = hp[1];
        float nm = nlut[pk >> 22];
        const f16x2* wp = wc + ((pk >> 17) & 31) * 8;
        float sd = 0.f;
        sd = FDOT2(asf16x2(u0.x), wp[0], sd);
        sd = FDOT2(asf16x2(u0.y), wp[1], sd);
        sd = FDOT2(asf16x2(u0.z), wp[2], sd);
        sd = FDOT2(asf16x2(u0.w), wp[3], sd);
        sd = FDOT2(asf16x2(u1.x), wp[4], sd);
        sd = FDOT2(asf16x2(u1.y), wp[5], sd);
        sd = FDOT2(asf16x2(u1.z), wp[6], sd);
        sd = FDOT2(asf16x2(u1.w), wp[7], sd);
        acc0 += nm * sd;
    }
    float acc = (acc0 + acc1) + (acc2 + acc3);
    float m = acc;
    #pragma unroll
    for (int mask = 1; mask < 8; mask <<= 1)
        m = fmaxf(m, __shfl_xor(m, mask, 8));
    float ex = expf(acc - m);
    float ssumv = ex;
    #pragma unroll
    for (int mask = 1; mask < 8; mask <<= 1)
        ssumv += __shfl_xor(ssumv, mask, 8);
    out[(size_t)d * CDIM + c] = acc - m - logf(ssumv);
}

extern "C" void kernel_launch(void* const* d_in, const int* in_sizes, int n_in,
                              void* d_out, int out_size, void* d_ws, size_t ws_size,
                              hipStream_t stream) {
    const float* emb = (const float*)d_in[0];
    const float* W1  = (const float*)d_in[1];
    const float* W2  = (const float*)d_in[2];
    const int* ei    = (const int*)d_in[3];
    const int* et    = (const int*)d_in[4];
    const int* srcp  = ei;
    const int* dstp  = ei + E_EDGES;

    char* ws = (char*)d_ws;
    size_t off = 0;
    #define ALIGN256(x) (((x) + 255) & ~(size_t)255)
    int* gcursor     = (int*)(ws + off); off = ALIGN256(off + 512 * 4);
    int* bucketstart = (int*)(ws + off); off = ALIGN256(off + 512 * 4);
    int* rowstart    = (int*)(ws + off); off = ALIGN256(off + ((size_t)N_NODES + 8) * 4);
    unsigned int* ebuf  = (unsigned int*)(ws + off); off = ALIGN256(off + (size_t)NBUCK * CAP * 4);
    unsigned int* elist = (unsigned int*)(ws + off); off = ALIGN256(off + (size_t)NBUCK * CAP * 4);
    unsigned short* BmT  = (unsigned short*)(ws + off); off = ALIGN256(off + (size_t)NOUT * F_IN * 2);
    unsigned short* ebf  = (unsigned short*)(ws + off); off = ALIGN256(off + (size_t)M_PAD * F_IN * 2);
    unsigned short* xw1  = (unsigned short*)(ws + off); off = ALIGN256(off + (size_t)M_PAD * NOUT * 2);
    _Float16* h          = (_Float16*)(ws + off);       off = ALIGN256(off + (size_t)N_NODES * HDIM * 2);
    float* out = (float*)d_out;

    hipMemsetAsync(gcursor, 0, 512 * 4, stream);

    k_front<<<FRONT_GRID, 512, 0, stream>>>(srcp, dstp, et, emb, W1, gcursor, ebuf, ebf, BmT);
    k_scanb<<<1, 512, 0, stream>>>(gcursor, bucketstart, rowstart);
    k_mid<<<MID_GRID, 256, 0, stream>>>(ebuf, gcursor, bucketstart, rowstart, elist, ebf, BmT, xw1);
    k_gather1<<<(N_NODES + 31) / 32, 256, 0, stream>>>(rowstart, elist, xw1, h);
    k_gather2<<<(N_NODES + 31) / 32, 256, 0, stream>>>(rowstart, elist, h, W2, out);
}

// Round 11
// 307.078 us; speedup vs baseline: 1.2749x; 1.0681x over previous
//
#include <hip/hip_runtime.h>
#include <hip/hip_bf16.h>
#include <math.h>

#define N_NODES 100000
#define R 32
#define E_EDGES 3200000
#define F_IN 128
#define HDIM 16
#define CDIM 8
#define NOUT 512               // R * HDIM
#define M_PAD 100032           // 1563 * 64
#define NBUCK 391              // ceil(N_NODES / 256)
#define CAP 9216               // bucket capacity: mean 8184, +11.4 sigma
#define KEYS 8192              // 256 nodes * 32 rels per bucket
#define P1CHUNK 8192
#define CVT_BLKS 6252          // M_PAD*F_IN/4 / 512
#define PREP_BLKS 128          // NOUT*F_IN / 512
#define FRONT_GRID (NBUCK + CVT_BLKS + PREP_BLKS)
#define GEMM_BLKS 1563         // M_PAD/64  (A-stationary: col loop inside)
#define MID_GRID (NBUCK + GEMM_BLKS)

typedef __attribute__((ext_vector_type(8))) short bf16x8;
typedef __attribute__((ext_vector_type(4))) float f32x4;
typedef __attribute__((ext_vector_type(2))) _Float16 f16x2;

static __device__ __forceinline__ unsigned short f2bf(float f) {
    unsigned int u = __float_as_uint(f);
    unsigned int r = (u + 0x7FFFu + ((u >> 16) & 1u)) >> 16;
    return (unsigned short)r;
}
static __device__ __forceinline__ float bfl(unsigned x) {
    return __uint_as_float(x << 16);
}
static __device__ __forceinline__ float bfh(unsigned x) {
    return __uint_as_float(x & 0xFFFF0000u);
}

#if __has_builtin(__builtin_amdgcn_fdot2)
static __device__ __forceinline__ float FDOT2(f16x2 a, f16x2 b, float c) {
    return __builtin_amdgcn_fdot2(a, b, c, false);
}
#else
static __device__ __forceinline__ float FDOT2(f16x2 a, f16x2 b, float c) {
    return c + (float)a.x * (float)b.x + (float)a.y * (float)b.y;
}
#endif

// ============ k_front: bucket-scatter ∥ emb->bf16 cvt ∥ W1 repack ============
// packed ebuf entry: dl(8b)<<22 | et(5b)<<17 | src(17b)
__global__ __launch_bounds__(512) void k_front(const int* __restrict__ src,
                                               const int* __restrict__ dst,
                                               const int* __restrict__ et,
                                               const float* __restrict__ emb,
                                               const float* __restrict__ W1,
                                               int* __restrict__ gcursor,
                                               unsigned int* __restrict__ ebuf,
                                               unsigned short* __restrict__ ebf,
                                               unsigned short* __restrict__ BmT) {
    __shared__ int sh[3 * NBUCK];
    int b = blockIdx.x, t = threadIdx.x;
    if (b < NBUCK) {
        int* hist = sh;
        int* rank = sh + NBUCK;
        int* base = sh + 2 * NBUCK;
        for (int j = t; j < NBUCK; j += 512) { hist[j] = 0; rank[j] = 0; }
        __syncthreads();
        int e0 = b * P1CHUNK;
        int e1 = e0 + P1CHUNK; if (e1 > E_EDGES) e1 = E_EDGES;
        int n4 = (e1 - e0) >> 2;
        const int4* d4 = (const int4*)(dst + e0);
        const int4* s4 = (const int4*)(src + e0);
        const int4* t4 = (const int4*)(et + e0);
        for (int i = t; i < n4; i += 512) {
            int4 v = d4[i];
            atomicAdd(&hist[v.x >> 8], 1);
            atomicAdd(&hist[v.y >> 8], 1);
            atomicAdd(&hist[v.z >> 8], 1);
            atomicAdd(&hist[v.w >> 8], 1);
        }
        __syncthreads();
        for (int j = t; j < NBUCK; j += 512)
            base[j] = hist[j] ? atomicAdd(&gcursor[j], hist[j]) : 0;
        __syncthreads();
        for (int i = t; i < n4; i += 512) {
            int4 dv = d4[i];
            int4 sv = s4[i];
            int4 tv = t4[i];
            int ds[4] = {dv.x, dv.y, dv.z, dv.w};
            int ss[4] = {sv.x, sv.y, sv.z, sv.w};
            int ts[4] = {tv.x, tv.y, tv.z, tv.w};
            #pragma unroll
            for (int u = 0; u < 4; ++u) {
                int d = ds[u];
                int bk = d >> 8;
                unsigned pk = ((unsigned)(d & 255) << 22) | ((unsigned)ts[u] << 17)
                            | (unsigned)ss[u];
                int lr = atomicAdd(&rank[bk], 1);
                ebuf[(size_t)bk * CAP + base[bk] + lr] = pk;
            }
        }
    } else if (b < NBUCK + CVT_BLKS) {
        // emb f32 -> bf16, rows padded to M_PAD with zeros; 1 float4-unit/thread
        size_t base = ((size_t)(b - NBUCK) * 512 + t) * 4;
        int row = (int)(base >> 7);
        ushort4 o;
        if (row < N_NODES) {
            float4 a = *(const float4*)(emb + base);
            o.x = f2bf(a.x); o.y = f2bf(a.y); o.z = f2bf(a.z); o.w = f2bf(a.w);
        } else {
            o.x = o.y = o.z = o.w = 0;
        }
        *(ushort4*)(ebf + base) = o;
    } else {
        // W1 [R,128,16] -> BmT bf16 [512][128] (n=r*16+o, k=f)
        int i = (b - NBUCK - CVT_BLKS) * 512 + t;
        int n = i >> 7;
        int f = i & 127;
        int r = n >> 4;
        int o = n & 15;
        BmT[i] = f2bf(W1[r * (F_IN * HDIM) + f * HDIM + o]);
    }
}

// ============ k_mid: per-bucket counting sort ∥ A-stationary MFMA GEMM ============
// final elist entry: len(10b)<<22 | et(5b)<<17 | src(17b); fixed bucket base b*CAP
__global__ __launch_bounds__(256) void k_mid(const unsigned int* __restrict__ ebuf,
                                             const int* __restrict__ gcursor,
                                             int2* __restrict__ rse,
                                             unsigned int* __restrict__ elist,
                                             const unsigned short* __restrict__ Abf,
                                             const unsigned short* __restrict__ BmT,
                                             unsigned short* __restrict__ C) {
    __shared__ __align__(16) char smem[34816 + 64];
    int b = blockIdx.x, t = threadIdx.x;
    if (b < NBUCK) {
        // ---- counting sort, 256 threads ----
        unsigned int* cnt = (unsigned int*)smem;       // 8192 * 4 = 32 KB
        int* wsum = (int*)(smem + 32768);              // 4 ints
        int cntE = gcursor[b];
        size_t e0 = (size_t)b * CAP;
        #pragma unroll
        for (int j = 0; j < KEYS / 256; ++j) cnt[t + j * 256] = 0;
        __syncthreads();
        for (int i = t; i < cntE; i += 256)
            atomicAdd(&cnt[ebuf[e0 + i] >> 17], 1u);   // key = dl*32 + et
        __syncthreads();
        int kbase = t * (KEYS / 256);
        int s = 0;
        #pragma unroll
        for (int j = 0; j < KEYS / 256; ++j) s += (int)cnt[kbase + j];
        int lane = t & 63, wv = t >> 6;
        int sc = s;
        #pragma unroll
        for (int off = 1; off < 64; off <<= 1) {
            int v = __shfl_up(sc, off, 64);
            if (lane >= off) sc += v;
        }
        if (lane == 63) wsum[wv] = sc;
        __syncthreads();
        if (t == 0) {
            int a = 0;
            #pragma unroll
            for (int w = 0; w < 4; ++w) { int v = wsum[w]; wsum[w] = a; a += v; }
        }
        __syncthreads();
        int run = wsum[wv] + sc - s;
        #pragma unroll
        for (int j = 0; j < KEYS / 256; ++j) {
            unsigned v = cnt[kbase + j];
            unsigned lc = v > 1023u ? 1023u : v;
            cnt[kbase + j] = (unsigned)run | (lc << 20);
            run += (int)v;
        }
        __syncthreads();
        {
            int d = b * 256 + t;
            if (d < N_NODES) {
                int rs = (int)(cnt[t * 32] & 0xFFFFFu);
                int re = (t < 255) ? (int)(cnt[(t + 1) * 32] & 0xFFFFFu) : cntE;
                rse[d] = make_int2((int)e0 + rs, (int)e0 + re);
            }
        }
        __syncthreads();
        for (int i = t; i < cntE; i += 256) {
            unsigned pk = ebuf[e0 + i];
            int key = pk >> 17;
            unsigned vv = atomicAdd(&cnt[key], 1u);
            int pos = (int)(vv & 0xFFFFFu);
            unsigned len = (vv >> 20) & 1023u;
            elist[e0 + pos] = (pk & 0x3FFFFFu) | (len << 22);
        }
    } else {
        // ---- A-stationary GEMM: stage 64x128 A once, loop 8 x 64-col tiles ----
        unsigned short* As = (unsigned short*)smem;            // 64*136*2 = 17408
        unsigned short* Bs = (unsigned short*)(smem + 17408);  // 64*136*2 = 17408
        int row0 = (b - NBUCK) * 64;
        #pragma unroll
        for (int j = 0; j < 4; ++j) {
            int idx = t + j * 256;            // 0..1023 8-elem units
            int r = idx >> 4;
            int u = idx & 15;
            float4 v = *(const float4*)(Abf + (size_t)(row0 + r) * F_IN + u * 8);
            *(float4*)(&As[r * 136 + u * 8]) = v;
        }
        int w = t >> 6;
        int lane = t & 63;
        int q = lane >> 4;
        int mr = lane & 15;
        const unsigned short* ap = &As[(w * 16 + mr) * 136 + q * 8];
        for (int col0 = 0; col0 < NOUT; col0 += 64) {
            __syncthreads();   // Bs free from previous iteration (covers As stage on first)
            #pragma unroll
            for (int j = 0; j < 4; ++j) {
                int idx = t + j * 256;            // 0..1023
                int r = idx >> 4;                 // 0..63
                int u = idx & 15;
                float4 v = *(const float4*)(BmT + (size_t)(col0 + r) * F_IN + u * 8);
                *(float4*)(&Bs[r * 136 + u * 8]) = v;
            }
            __syncthreads();
            f32x4 acc[4] = {};
            #pragma unroll
            for (int kk = 0; kk < 4; ++kk) {
                bf16x8 af = *(const bf16x8*)(ap + kk * 32);
                #pragma unroll
                for (int tt = 0; tt < 4; ++tt) {
                    bf16x8 bf = *(const bf16x8*)(&Bs[(tt * 16 + mr) * 136 + q * 8 + kk * 32]);
                    acc[tt] = __builtin_amdgcn_mfma_f32_16x16x32_bf16(af, bf, acc[tt], 0, 0, 0);
                }
            }
            #pragma unroll
            for (int tt = 0; tt < 4; ++tt) {
                #pragma unroll
                for (int j = 0; j < 4; ++j) {
                    int row = row0 + w * 16 + q * 4 + j;
                    C[(size_t)row * NOUT + col0 + tt * 16 + mr] = f2bf(acc[tt][j]);
                }
            }
        }
    }
}

// ============ gather1: 8 lanes/node, 4 B loads, 4-edge unroll, h f16 ============
__global__ __launch_bounds__(256) void k_gather1(const int2* __restrict__ rse,
                                                 const unsigned int* __restrict__ elist,
                                                 const unsigned short* __restrict__ xw1,
                                                 _Float16* __restrict__ h) {
    __shared__ float nlut[1024];
    int t = threadIdx.x;
    for (int j = t; j < 1024; j += 256) nlut[j] = 1.0f / (float)(j ? j : 1);
    __syncthreads();
    int g = t >> 3;            // node in block, 0..31
    int c = t & 7;             // channel pair: elems c*2, c*2+1
    int d = blockIdx.x * 32 + g;
    if (d >= N_NODES) return;
    int2 rr = rse[d];
    int i = rr.x, end = rr.y;
    float a0 = 0.f, a1 = 0.f, b0 = 0.f, b1 = 0.f;
    float c0 = 0.f, c1 = 0.f, e0 = 0.f, e1 = 0.f;
    for (; i + 3 < end; i += 4) {
        unsigned pk0 = elist[i];
        unsigned pk1 = elist[i + 1];
        unsigned pk2 = elist[i + 2];
        unsigned pk3 = elist[i + 3];
        unsigned x0 = *(const unsigned*)(xw1 + (size_t)(pk0 & 0x1FFFF) * NOUT + ((pk0 >> 17) & 31) * HDIM + c * 2);
        unsigned x1 = *(const unsigned*)(xw1 + (size_t)(pk1 & 0x1FFFF) * NOUT + ((pk1 >> 17) & 31) * HDIM + c * 2);
        unsigned x2 = *(const unsigned*)(xw1 + (size_t)(pk2 & 0x1FFFF) * NOUT + ((pk2 >> 17) & 31) * HDIM + c * 2);
        unsigned x3 = *(const unsigned*)(xw1 + (size_t)(pk3 & 0x1FFFF) * NOUT + ((pk3 >> 17) & 31) * HDIM + c * 2);
        float n0 = nlut[pk0 >> 22], n1 = nlut[pk1 >> 22];
        float n2 = nlut[pk2 >> 22], n3 = nlut[pk3 >> 22];
        a0 += bfl(x0) * n0; a1 += bfh(x0) * n0;
        b0 += bfl(x1) * n1; b1 += bfh(x1) * n1;
        c0 += bfl(x2) * n2; c1 += bfh(x2) * n2;
        e0 += bfl(x3) * n3; e1 += bfh(x3) * n3;
    }
    for (; i < end; ++i) {
        unsigned pk = elist[i];
        unsigned x = *(const unsigned*)(xw1 + (size_t)(pk & 0x1FFFF) * NOUT + ((pk >> 17) & 31) * HDIM + c * 2);
        float nm = nlut[pk >> 22];
        a0 += bfl(x) * nm; a1 += bfh(x) * nm;
    }
    f16x2 o;
    o.x = (_Float16)fmaxf(a0 + b0 + c0 + e0, 0.f);
    o.y = (_Float16)fmaxf(a1 + b1 + c1 + e1, 0.f);
    *(f16x2*)(h + (size_t)d * HDIM + c * 2) = o;
}

// ============ gather2: channel-split lanes + transpose-reduce + log_softmax ============
// lane ch of 8 loads h channels (2ch,2ch+1) only (4 B, coalesced 32 B/edge).
// acc[cls] per lane accumulates FDOT2(h2 * nm, W2[r][2ch:2ch+2][cls]).
// End: 8x8 butterfly transpose-reduce; lane ch keeps class ch.
__global__ __launch_bounds__(256) void k_gather2(const int2* __restrict__ rse,
                                                 const unsigned int* __restrict__ elist,
                                                 const _Float16* __restrict__ h,
                                                 const float* __restrict__ W2,
                                                 float* __restrict__ out) {
    __shared__ f16x2 w2cl[8 * 264];   // [ch][r*8+cls], plane stride 264 (banks +8/ch)
    __shared__ f16x2 nlutH[1024];
    int t = threadIdx.x;
    for (int j = t; j < 1024; j += 256) {
        float nm = 1.0f / (float)(j ? j : 1);
        f16x2 p; p.x = (_Float16)nm; p.y = (_Float16)nm;
        nlutH[j] = p;
    }
    #pragma unroll
    for (int j = 0; j < 8; ++j) {
        int idx = t + j * 256;           // 0..2047
        int ch = idx >> 8;               // 0..7
        int r = (idx >> 3) & 31;
        int cls = idx & 7;
        f16x2 p;
        p.x = (_Float16)W2[r * 128 + (2 * ch) * 8 + cls];
        p.y = (_Float16)W2[r * 128 + (2 * ch + 1) * 8 + cls];
        w2cl[ch * 264 + r * 8 + cls] = p;
    }
    __syncthreads();

    int g = t >> 3;
    int ch = t & 7;
    int d = blockIdx.x * 32 + g;
    if (d >= N_NODES) return;
    const f16x2* wbase = &w2cl[ch * 264];
    int2 rr = rse[d];
    int i = rr.x, end = rr.y;
    float acc[8] = {};
    for (; i + 3 < end; i += 4) {
        unsigned pk0 = elist[i];
        unsigned pk1 = elist[i + 1];
        unsigned pk2 = elist[i + 2];
        unsigned pk3 = elist[i + 3];
        f16x2 h0 = *(const f16x2*)(h + (size_t)(pk0 & 0x1FFFF) * HDIM + ch * 2);
        f16x2 h1 = *(const f16x2*)(h + (size_t)(pk1 & 0x1FFFF) * HDIM + ch * 2);
        f16x2 h2 = *(const f16x2*)(h + (size_t)(pk2 & 0x1FFFF) * HDIM + ch * 2);
        f16x2 h3 = *(const f16x2*)(h + (size_t)(pk3 & 0x1FFFF) * HDIM + ch * 2);
        h0 *= nlutH[pk0 >> 22];
        h1 *= nlutH[pk1 >> 22];
        h2 *= nlutH[pk2 >> 22];
        h3 *= nlutH[pk3 >> 22];
        const f16x2* w0 = wbase + ((pk0 >> 17) & 31) * 8;
        const f16x2* w1 = wbase + ((pk1 >> 17) & 31) * 8;
        const f16x2* w2 = wbase + ((pk2 >> 17) & 31) * 8;
        const f16x2* w3 = wbase + ((pk3 >> 17) & 31) * 8;
        #pragma unroll
        for (int k = 0; k < 8; ++k) {
            acc[k] = FDOT2(h0, w0[k], acc[k]);
            acc[k] = FDOT2(h1, w1[k], acc[k]);
            acc[k] = FDOT2(h2, w2[k], acc[k]);
            acc[k] = FDOT2(h3, w3[k], acc[k]);
        }
    }
    for (; i < end; ++i) {
        unsigned pk = elist[i];
        f16x2 hv = *(const f16x2*)(h + (size_t)(pk & 0x1FFFF) * HDIM + ch * 2);
        hv *= nlutH[pk >> 22];
        const f16x2* wp = wbase + ((pk >> 17) & 31) * 8;
        #pragma unroll
        for (int k = 0; k < 8; ++k)
            acc[k] = FDOT2(hv, wp[k], acc[k]);
    }
    // butterfly: every lane ends with full per-class sums over the 8 channel-lanes
    #pragma unroll
    for (int mask = 1; mask < 8; mask <<= 1) {
        #pragma unroll
        for (int k = 0; k < 8; ++k)
            acc[k] += __shfl_xor(acc[k], mask, 8);
    }
    float v = acc[ch];
    float m = v;
    #pragma unroll
    for (int mask = 1; mask < 8; mask <<= 1)
        m = fmaxf(m, __shfl_xor(m, mask, 8));
    float ex = expf(v - m);
    float ssumv = ex;
    #pragma unroll
    for (int mask = 1; mask < 8; mask <<= 1)
        ssumv += __shfl_xor(ssumv, mask, 8);
    out[(size_t)d * CDIM + ch] = v - m - logf(ssumv);
}

extern "C" void kernel_launch(void* const* d_in, const int* in_sizes, int n_in,
                              void* d_out, int out_size, void* d_ws, size_t ws_size,
                              hipStream_t stream) {
    const float* emb = (const float*)d_in[0];
    const float* W1  = (const float*)d_in[1];
    const float* W2  = (const float*)d_in[2];
    const int* ei    = (const int*)d_in[3];
    const int* et    = (const int*)d_in[4];
    const int* srcp  = ei;
    const int* dstp  = ei + E_EDGES;

    char* ws = (char*)d_ws;
    size_t off = 0;
    #define ALIGN256(x) (((x) + 255) & ~(size_t)255)
    int* gcursor     = (int*)(ws + off); off = ALIGN256(off + 512 * 4);
    int2* rse        = (int2*)(ws + off); off = ALIGN256(off + ((size_t)N_NODES + 8) * 8);
    unsigned int* ebuf  = (unsigned int*)(ws + off); off = ALIGN256(off + (size_t)NBUCK * CAP * 4);
    unsigned int* elist = (unsigned int*)(ws + off); off = ALIGN256(off + (size_t)NBUCK * CAP * 4);
    unsigned short* BmT  = (unsigned short*)(ws + off); off = ALIGN256(off + (size_t)NOUT * F_IN * 2);
    unsigned short* ebf  = (unsigned short*)(ws + off); off = ALIGN256(off + (size_t)M_PAD * F_IN * 2);
    unsigned short* xw1  = (unsigned short*)(ws + off); off = ALIGN256(off + (size_t)M_PAD * NOUT * 2);
    _Float16* h          = (_Float16*)(ws + off);       off = ALIGN256(off + (size_t)N_NODES * HDIM * 2);
    float* out = (float*)d_out;

    hipMemsetAsync(gcursor, 0, 512 * 4, stream);

    k_front<<<FRONT_GRID, 512, 0, stream>>>(srcp, dstp, et, emb, W1, gcursor, ebuf, ebf, BmT);
    k_mid<<<MID_GRID, 256, 0, stream>>>(ebuf, gcursor, rse, elist, ebf, BmT, xw1);
    k_gather1<<<(N_NODES + 31) / 32, 256, 0, stream>>>(rse, elist, xw1, h);
    k_gather2<<<(N_NODES + 31) / 32, 256, 0, stream>>>(rse, elist, h, W2, out);
}

// Round 12
// 296.959 us; speedup vs baseline: 1.3183x; 1.0341x over previous
//
#include <hip/hip_runtime.h>
#include <hip/hip_bf16.h>
#include <math.h>

#define N_NODES 100000
#define R 32
#define E_EDGES 3200000
#define F_IN 128
#define HDIM 16
#define CDIM 8
#define NOUT 512               // R * HDIM
#define M_PAD 100096           // 782 * 128
#define NBUCK 391              // ceil(N_NODES / 256)
#define CAP 9216               // bucket capacity: mean 8184, +11.4 sigma
#define KEYS 8192              // 256 nodes * 32 rels per bucket
#define P1CHUNK 8192
#define CVT_BLKS 6256          // M_PAD*F_IN/4 / 512
#define PREP_BLKS 128          // NOUT*F_IN / 512
#define FRONT_GRID (NBUCK + CVT_BLKS + PREP_BLKS)
#define GEMM_BLKS 782          // M_PAD/128  (A-stationary: col loop inside)
#define MID_GRID (NBUCK + GEMM_BLKS)

typedef __attribute__((ext_vector_type(8))) short bf16x8;
typedef __attribute__((ext_vector_type(4))) float f32x4;
typedef __attribute__((ext_vector_type(2))) _Float16 f16x2;

static __device__ __forceinline__ unsigned short f2bf(float f) {
    unsigned int u = __float_as_uint(f);
    unsigned int r = (u + 0x7FFFu + ((u >> 16) & 1u)) >> 16;
    return (unsigned short)r;
}
static __device__ __forceinline__ float bfl(unsigned x) {
    return __uint_as_float(x << 16);
}
static __device__ __forceinline__ float bfh(unsigned x) {
    return __uint_as_float(x & 0xFFFF0000u);
}

#if __has_builtin(__builtin_amdgcn_fdot2)
static __device__ __forceinline__ float FDOT2(f16x2 a, f16x2 b, float c) {
    return __builtin_amdgcn_fdot2(a, b, c, false);
}
#else
static __device__ __forceinline__ float FDOT2(f16x2 a, f16x2 b, float c) {
    return c + (float)a.x * (float)b.x + (float)a.y * (float)b.y;
}
#endif

// ============ k_front: bucket-scatter (reg-held pass 2) ∥ emb cvt ∥ W1 repack ============
// packed ebuf entry: dl(8b)<<22 | et(5b)<<17 | src(17b)
__global__ __launch_bounds__(512) void k_front(const int* __restrict__ src,
                                               const int* __restrict__ dst,
                                               const int* __restrict__ et,
                                               const float* __restrict__ emb,
                                               const float* __restrict__ W1,
                                               int* __restrict__ gcursor,
                                               unsigned int* __restrict__ ebuf,
                                               unsigned short* __restrict__ ebf,
                                               unsigned short* __restrict__ BmT) {
    __shared__ int sh[3 * NBUCK];
    int b = blockIdx.x, t = threadIdx.x;
    if (b < NBUCK) {
        int* hist = sh;
        int* rank = sh + NBUCK;
        int* base = sh + 2 * NBUCK;
        for (int j = t; j < NBUCK; j += 512) { hist[j] = 0; rank[j] = 0; }
        __syncthreads();
        int e0 = b * P1CHUNK;
        int e1 = e0 + P1CHUNK; if (e1 > E_EDGES) e1 = E_EDGES;
        int n4 = (e1 - e0) >> 2;
        const int4* d4 = (const int4*)(dst + e0);
        const int4* s4 = (const int4*)(src + e0);
        const int4* t4 = (const int4*)(et + e0);
        unsigned pkreg[16];                 // <=4 iterations x 4 edges held in regs
        int j = 0;
        for (int i = t; i < n4; i += 512, ++j) {
            int4 dv = d4[i];
            int4 sv = s4[i];
            int4 tv = t4[i];
            int ds[4] = {dv.x, dv.y, dv.z, dv.w};
            int ss[4] = {sv.x, sv.y, sv.z, sv.w};
            int ts[4] = {tv.x, tv.y, tv.z, tv.w};
            #pragma unroll
            for (int u = 0; u < 4; ++u) {
                atomicAdd(&hist[ds[u] >> 8], 1);
                pkreg[j * 4 + u] = ((unsigned)(ds[u] & 255) << 22)
                                 | ((unsigned)ts[u] << 17) | (unsigned)ss[u];
            }
        }
        __syncthreads();
        for (int k = t; k < NBUCK; k += 512)
            base[k] = hist[k] ? atomicAdd(&gcursor[k], hist[k]) : 0;
        __syncthreads();
        j = 0;
        for (int i = t; i < n4; i += 512, ++j) {
            int4 dv = d4[i];                 // re-read dst only (L2-hot)
            int ds[4] = {dv.x, dv.y, dv.z, dv.w};
            #pragma unroll
            for (int u = 0; u < 4; ++u) {
                int bk = ds[u] >> 8;
                int lr = atomicAdd(&rank[bk], 1);
                ebuf[(size_t)bk * CAP + base[bk] + lr] = pkreg[j * 4 + u];
            }
        }
    } else if (b < NBUCK + CVT_BLKS) {
        // emb f32 -> bf16, rows padded to M_PAD with zeros; 1 float4-unit/thread
        size_t base = ((size_t)(b - NBUCK) * 512 + t) * 4;
        int row = (int)(base >> 7);
        ushort4 o;
        if (row < N_NODES) {
            float4 a = *(const float4*)(emb + base);
            o.x = f2bf(a.x); o.y = f2bf(a.y); o.z = f2bf(a.z); o.w = f2bf(a.w);
        } else {
            o.x = o.y = o.z = o.w = 0;
        }
        *(ushort4*)(ebf + base) = o;
    } else {
        // W1 [R,128,16] -> BmT bf16 [512][128] (n=r*16+o, k=f)
        int i = (b - NBUCK - CVT_BLKS) * 512 + t;
        int n = i >> 7;
        int f = i & 127;
        int r = n >> 4;
        int o = n & 15;
        BmT[i] = f2bf(W1[r * (F_IN * HDIM) + f * HDIM + o]);
    }
}

// ============ k_mid (512 thr): per-bucket counting sort ∥ A-stationary MFMA GEMM ============
// final elist entry: len(10b)<<22 | et(5b)<<17 | src(17b); fixed bucket base b*CAP
__global__ __launch_bounds__(512) void k_mid(const unsigned int* __restrict__ ebuf,
                                             const int* __restrict__ gcursor,
                                             int2* __restrict__ rse,
                                             unsigned int* __restrict__ elist,
                                             const unsigned short* __restrict__ Abf,
                                             const unsigned short* __restrict__ BmT,
                                             unsigned short* __restrict__ C) {
    __shared__ __align__(16) char smem[52224 + 64];
    int b = blockIdx.x, t = threadIdx.x;
    if (b < NBUCK) {
        // ---- counting sort, 512 threads ----
        unsigned int* cnt = (unsigned int*)smem;       // 8192 * 4 = 32 KB
        int* wsum = (int*)(smem + 32768);              // 8 ints
        int cntE = gcursor[b];
        size_t e0 = (size_t)b * CAP;
        #pragma unroll
        for (int j = 0; j < KEYS / 512; ++j) cnt[t + j * 512] = 0;
        __syncthreads();
        for (int i = t; i < cntE; i += 512)
            atomicAdd(&cnt[ebuf[e0 + i] >> 17], 1u);   // key = dl*32 + et
        __syncthreads();
        int kbase = t * (KEYS / 512);                  // 16 keys/thread
        int s = 0;
        #pragma unroll
        for (int j = 0; j < KEYS / 512; ++j) s += (int)cnt[kbase + j];
        int lane = t & 63, wv = t >> 6;                // 8 waves
        int sc = s;
        #pragma unroll
        for (int off = 1; off < 64; off <<= 1) {
            int v = __shfl_up(sc, off, 64);
            if (lane >= off) sc += v;
        }
        if (lane == 63) wsum[wv] = sc;
        __syncthreads();
        if (t == 0) {
            int a = 0;
            #pragma unroll
            for (int w = 0; w < 8; ++w) { int v = wsum[w]; wsum[w] = a; a += v; }
        }
        __syncthreads();
        int run = wsum[wv] + sc - s;
        #pragma unroll
        for (int j = 0; j < KEYS / 512; ++j) {
            unsigned v = cnt[kbase + j];
            unsigned lc = v > 1023u ? 1023u : v;
            cnt[kbase + j] = (unsigned)run | (lc << 20);
            run += (int)v;
        }
        __syncthreads();
        if (t < 256) {
            int d = b * 256 + t;
            if (d < N_NODES) {
                int rs = (int)(cnt[t * 32] & 0xFFFFFu);
                int re = (t < 255) ? (int)(cnt[(t + 1) * 32] & 0xFFFFFu) : cntE;
                rse[d] = make_int2((int)e0 + rs, (int)e0 + re);
            }
        }
        __syncthreads();
        for (int i = t; i < cntE; i += 512) {
            unsigned pk = ebuf[e0 + i];
            int key = pk >> 17;
            unsigned vv = atomicAdd(&cnt[key], 1u);
            int pos = (int)(vv & 0xFFFFFu);
            unsigned len = (vv >> 20) & 1023u;
            elist[e0 + pos] = (pk & 0x3FFFFFu) | (len << 22);
        }
    } else {
        // ---- A-stationary GEMM: 128-row A tile (8 waves), loop 8 x 64-col B tiles ----
        unsigned short* As = (unsigned short*)smem;            // 128*136*2 = 34816
        unsigned short* Bs = (unsigned short*)(smem + 34816);  // 64*136*2  = 17408
        int row0 = (b - NBUCK) * 128;
        #pragma unroll
        for (int j = 0; j < 4; ++j) {
            int idx = t + j * 512;            // 0..2047 8-elem units
            int r = idx >> 4;                 // 0..127
            int u = idx & 15;
            float4 v = *(const float4*)(Abf + (size_t)(row0 + r) * F_IN + u * 8);
            *(float4*)(&As[r * 136 + u * 8]) = v;
        }
        int w = t >> 6;        // wave 0..7 -> rows [16w,16w+16)
        int lane = t & 63;
        int q = lane >> 4;
        int mr = lane & 15;
        const unsigned short* ap = &As[(w * 16 + mr) * 136 + q * 8];
        for (int col0 = 0; col0 < NOUT; col0 += 64) {
            __syncthreads();   // Bs free from previous iteration (covers As stage on first)
            #pragma unroll
            for (int j = 0; j < 2; ++j) {
                int idx = t + j * 512;            // 0..1023
                int r = idx >> 4;                 // 0..63
                int u = idx & 15;
                float4 v = *(const float4*)(BmT + (size_t)(col0 + r) * F_IN + u * 8);
                *(float4*)(&Bs[r * 136 + u * 8]) = v;
            }
            __syncthreads();
            f32x4 acc[4] = {};
            #pragma unroll
            for (int kk = 0; kk < 4; ++kk) {
                bf16x8 af = *(const bf16x8*)(ap + kk * 32);
                #pragma unroll
                for (int tt = 0; tt < 4; ++tt) {
                    bf16x8 bf = *(const bf16x8*)(&Bs[(tt * 16 + mr) * 136 + q * 8 + kk * 32]);
                    acc[tt] = __builtin_amdgcn_mfma_f32_16x16x32_bf16(af, bf, acc[tt], 0, 0, 0);
                }
            }
            #pragma unroll
            for (int tt = 0; tt < 4; ++tt) {
                #pragma unroll
                for (int j = 0; j < 4; ++j) {
                    int row = row0 + w * 16 + q * 4 + j;
                    C[(size_t)row * NOUT + col0 + tt * 16 + mr] = f2bf(acc[tt][j]);
                }
            }
        }
    }
}

// ============ gather1: 8 lanes/node, 4 B loads, 4-edge unroll, h f16 ============
__global__ __launch_bounds__(256) void k_gather1(const int2* __restrict__ rse,
                                                 const unsigned int* __restrict__ elist,
                                                 const unsigned short* __restrict__ xw1,
                                                 _Float16* __restrict__ h) {
    __shared__ float nlut[1024];
    int t = threadIdx.x;
    for (int j = t; j < 1024; j += 256) nlut[j] = 1.0f / (float)(j ? j : 1);
    __syncthreads();
    int g = t >> 3;            // node in block, 0..31
    int c = t & 7;             // channel pair: elems c*2, c*2+1
    int d = blockIdx.x * 32 + g;
    if (d >= N_NODES) return;
    int2 rr = rse[d];
    int i = rr.x, end = rr.y;
    float a0 = 0.f, a1 = 0.f, b0 = 0.f, b1 = 0.f;
    float c0 = 0.f, c1 = 0.f, e0 = 0.f, e1 = 0.f;
    for (; i + 3 < end; i += 4) {
        unsigned pk0 = elist[i];
        unsigned pk1 = elist[i + 1];
        unsigned pk2 = elist[i + 2];
        unsigned pk3 = elist[i + 3];
        unsigned x0 = *(const unsigned*)(xw1 + (size_t)(pk0 & 0x1FFFF) * NOUT + ((pk0 >> 17) & 31) * HDIM + c * 2);
        unsigned x1 = *(const unsigned*)(xw1 + (size_t)(pk1 & 0x1FFFF) * NOUT + ((pk1 >> 17) & 31) * HDIM + c * 2);
        unsigned x2 = *(const unsigned*)(xw1 + (size_t)(pk2 & 0x1FFFF) * NOUT + ((pk2 >> 17) & 31) * HDIM + c * 2);
        unsigned x3 = *(const unsigned*)(xw1 + (size_t)(pk3 & 0x1FFFF) * NOUT + ((pk3 >> 17) & 31) * HDIM + c * 2);
        float n0 = nlut[pk0 >> 22], n1 = nlut[pk1 >> 22];
        float n2 = nlut[pk2 >> 22], n3 = nlut[pk3 >> 22];
        a0 += bfl(x0) * n0; a1 += bfh(x0) * n0;
        b0 += bfl(x1) * n1; b1 += bfh(x1) * n1;
        c0 += bfl(x2) * n2; c1 += bfh(x2) * n2;
        e0 += bfl(x3) * n3; e1 += bfh(x3) * n3;
    }
    for (; i < end; ++i) {
        unsigned pk = elist[i];
        unsigned x = *(const unsigned*)(xw1 + (size_t)(pk & 0x1FFFF) * NOUT + ((pk >> 17) & 31) * HDIM + c * 2);
        float nm = nlut[pk >> 22];
        a0 += bfl(x) * nm; a1 += bfh(x) * nm;
    }
    f16x2 o;
    o.x = (_Float16)fmaxf(a0 + b0 + c0 + e0, 0.f);
    o.y = (_Float16)fmaxf(a1 + b1 + c1 + e1, 0.f);
    *(f16x2*)(h + (size_t)d * HDIM + c * 2) = o;
}

// ============ gather2: channel-split lanes + transpose-reduce + log_softmax ============
__global__ __launch_bounds__(256) void k_gather2(const int2* __restrict__ rse,
                                                 const unsigned int* __restrict__ elist,
                                                 const _Float16* __restrict__ h,
                                                 const float* __restrict__ W2,
                                                 float* __restrict__ out) {
    __shared__ f16x2 w2cl[8 * 264];   // [ch][r*8+cls], plane stride 264 (banks +8/ch)
    __shared__ f16x2 nlutH[1024];
    int t = threadIdx.x;
    for (int j = t; j < 1024; j += 256) {
        float nm = 1.0f / (float)(j ? j : 1);
        f16x2 p; p.x = (_Float16)nm; p.y = (_Float16)nm;
        nlutH[j] = p;
    }
    #pragma unroll
    for (int j = 0; j < 8; ++j) {
        int idx = t + j * 256;           // 0..2047
        int ch = idx >> 8;               // 0..7
        int r = (idx >> 3) & 31;
        int cls = idx & 7;
        f16x2 p;
        p.x = (_Float16)W2[r * 128 + (2 * ch) * 8 + cls];
        p.y = (_Float16)W2[r * 128 + (2 * ch + 1) * 8 + cls];
        w2cl[ch * 264 + r * 8 + cls] = p;
    }
    __syncthreads();

    int g = t >> 3;
    int ch = t & 7;
    int d = blockIdx.x * 32 + g;
    if (d >= N_NODES) return;
    const f16x2* wbase = &w2cl[ch * 264];
    int2 rr = rse[d];
    int i = rr.x, end = rr.y;
    float acc[8] = {};
    for (; i + 3 < end; i += 4) {
        unsigned pk0 = elist[i];
        unsigned pk1 = elist[i + 1];
        unsigned pk2 = elist[i + 2];
        unsigned pk3 = elist[i + 3];
        f16x2 h0 = *(const f16x2*)(h + (size_t)(pk0 & 0x1FFFF) * HDIM + ch * 2);
        f16x2 h1 = *(const f16x2*)(h + (size_t)(pk1 & 0x1FFFF) * HDIM + ch * 2);
        f16x2 h2 = *(const f16x2*)(h + (size_t)(pk2 & 0x1FFFF) * HDIM + ch * 2);
        f16x2 h3 = *(const f16x2*)(h + (size_t)(pk3 & 0x1FFFF) * HDIM + ch * 2);
        h0 *= nlutH[pk0 >> 22];
        h1 *= nlutH[pk1 >> 22];
        h2 *= nlutH[pk2 >> 22];
        h3 *= nlutH[pk3 >> 22];
        const f16x2* w0 = wbase + ((pk0 >> 17) & 31) * 8;
        const f16x2* w1 = wbase + ((pk1 >> 17) & 31) * 8;
        const f16x2* w2 = wbase + ((pk2 >> 17) & 31) * 8;
        const f16x2* w3 = wbase + ((pk3 >> 17) & 31) * 8;
        #pragma unroll
        for (int k = 0; k < 8; ++k) {
            acc[k] = FDOT2(h0, w0[k], acc[k]);
            acc[k] = FDOT2(h1, w1[k], acc[k]);
            acc[k] = FDOT2(h2, w2[k], acc[k]);
            acc[k] = FDOT2(h3, w3[k], acc[k]);
        }
    }
    for (; i < end; ++i) {
        unsigned pk = elist[i];
        f16x2 hv = *(const f16x2*)(h + (size_t)(pk & 0x1FFFF) * HDIM + ch * 2);
        hv *= nlutH[pk >> 22];
        const f16x2* wp = wbase + ((pk >> 17) & 31) * 8;
        #pragma unroll
        for (int k = 0; k < 8; ++k)
            acc[k] = FDOT2(hv, wp[k], acc[k]);
    }
    #pragma unroll
    for (int mask = 1; mask < 8; mask <<= 1) {
        #pragma unroll
        for (int k = 0; k < 8; ++k)
            acc[k] += __shfl_xor(acc[k], mask, 8);
    }
    float v = acc[ch];
    float m = v;
    #pragma unroll
    for (int mask = 1; mask < 8; mask <<= 1)
        m = fmaxf(m, __shfl_xor(m, mask, 8));
    float ex = expf(v - m);
    float ssumv = ex;
    #pragma unroll
    for (int mask = 1; mask < 8; mask <<= 1)
        ssumv += __shfl_xor(ssumv, mask, 8);
    out[(size_t)d * CDIM + ch] = v - m - logf(ssumv);
}

extern "C" void kernel_launch(void* const* d_in, const int* in_sizes, int n_in,
                              void* d_out, int out_size, void* d_ws, size_t ws_size,
                              hipStream_t stream) {
    const float* emb = (const float*)d_in[0];
    const float* W1  = (const float*)d_in[1];
    const float* W2  = (const float*)d_in[2];
    const int* ei    = (const int*)d_in[3];
    const int* et    = (const int*)d_in[4];
    const int* srcp  = ei;
    const int* dstp  = ei + E_EDGES;

    char* ws = (char*)d_ws;
    size_t off = 0;
    #define ALIGN256(x) (((x) + 255) & ~(size_t)255)
    int* gcursor     = (int*)(ws + off); off = ALIGN256(off + 512 * 4);
    int2* rse        = (int2*)(ws + off); off = ALIGN256(off + ((size_t)N_NODES + 8) * 8);
    unsigned int* ebuf  = (unsigned int*)(ws + off); off = ALIGN256(off + (size_t)NBUCK * CAP * 4);
    unsigned int* elist = (unsigned int*)(ws + off); off = ALIGN256(off + (size_t)NBUCK * CAP * 4);
    unsigned short* BmT  = (unsigned short*)(ws + off); off = ALIGN256(off + (size_t)NOUT * F_IN * 2);
    unsigned short* ebf  = (unsigned short*)(ws + off); off = ALIGN256(off + (size_t)M_PAD * F_IN * 2);
    unsigned short* xw1  = (unsigned short*)(ws + off); off = ALIGN256(off + (size_t)M_PAD * NOUT * 2);
    _Float16* h          = (_Float16*)(ws + off);       off = ALIGN256(off + (size_t)N_NODES * HDIM * 2);
    float* out = (float*)d_out;

    hipMemsetAsync(gcursor, 0, 512 * 4, stream);

    k_front<<<FRONT_GRID, 512, 0, stream>>>(srcp, dstp, et, emb, W1, gcursor, ebuf, ebf, BmT);
    k_mid<<<MID_GRID, 512, 0, stream>>>(ebuf, gcursor, rse, elist, ebf, BmT, xw1);
    k_gather1<<<(N_NODES + 31) / 32, 256, 0, stream>>>(rse, elist, xw1, h);
    k_gather2<<<(N_NODES + 31) / 32, 256, 0, stream>>>(rse, elist, h, W2, out);
}